// Round 3
// baseline (531.354 us; speedup 1.0000x reference)
//
#include <hip/hip_runtime.h>
#include <hip/hip_cooperative_groups.h>
#include <cstdint>
#include <cstddef>

namespace cg = cooperative_groups;

typedef __bf16 bf16x8 __attribute__((ext_vector_type(8)));
typedef float  f32x4  __attribute__((ext_vector_type(4)));

#define TT 8192
#define EE 1024
#define LDSK 40    // small-path padded LDS stride (shorts)

__device__ __forceinline__ unsigned short f2bf(float f) {
    union { float f; unsigned int u; } v; v.f = f;
    unsigned int r = v.u + 0x7FFFu + ((v.u >> 16) & 1u);
    return (unsigned short)(r >> 16);
}
__device__ __forceinline__ float b2f(unsigned int h) {
    union { unsigned int u; float f; } v; v.u = h << 16; return v.f;
}
__device__ __forceinline__ void gload_lds16(const void* g, void* l) {
    __builtin_amdgcn_global_load_lds((__attribute__((address_space(1))) void*)g,
                                     (__attribute__((address_space(3))) void*)l, 16, 0, 0);
}

// ---------------------------------------------------------------------------
// Standalone W transpose (small path). grid (32,32,4), block (32,8).
// ---------------------------------------------------------------------------
__global__ void wt_kernel(const float* __restrict__ Wk, const float* __restrict__ Wv,
                          const float* __restrict__ Wr, const float* __restrict__ Wo,
                          unsigned short* __restrict__ Tk, unsigned short* __restrict__ Tv,
                          unsigned short* __restrict__ Tr, unsigned short* __restrict__ To) {
    __shared__ float tile[32][33];
    const float* W; unsigned short* D;
    switch (blockIdx.z) {
        case 0:  W = Wk; D = Tk; break;
        case 1:  W = Wv; D = Tv; break;
        case 2:  W = Wr; D = Tr; break;
        default: W = Wo; D = To; break;
    }
    const int bx = blockIdx.x * 32, by = blockIdx.y * 32;
    const int tx = threadIdx.x, ty = threadIdx.y;
#pragma unroll
    for (int r = 0; r < 4; ++r)
        tile[ty + 8 * r][tx] = W[(size_t)(by + ty + 8 * r) * EE + bx + tx];
    __syncthreads();
#pragma unroll
    for (int r = 0; r < 4; ++r)
        D[(size_t)(bx + ty + 8 * r) * EE + by + tx] = f2bf(tile[tx][ty + 8 * r]);
}

// ---------------------------------------------------------------------------
// Fused prep: blocks [0,4096) transpose 4 Ws; blocks [4096,12288) token-shift
// mix -> bf16 kx/vx/rx.  1D grid 12288, block 256.
// ---------------------------------------------------------------------------
__global__ void prep_kernel(const float* __restrict__ Wk, const float* __restrict__ Wv,
                            const float* __restrict__ Wr, const float* __restrict__ Wo,
                            unsigned short* __restrict__ Tk, unsigned short* __restrict__ Tv,
                            unsigned short* __restrict__ Tr, unsigned short* __restrict__ To,
                            const float* __restrict__ x, const float* __restrict__ sx,
                            const float* __restrict__ tmk, const float* __restrict__ tmv,
                            const float* __restrict__ tmr,
                            unsigned short* __restrict__ kxb, unsigned short* __restrict__ vxb,
                            unsigned short* __restrict__ rxb) {
    const int bid = blockIdx.x;
    if (bid < 4096) {
        __shared__ float tile[32][33];
        const int z = bid >> 10;
        const float* W; unsigned short* D;
        switch (z) {
            case 0:  W = Wk; D = Tk; break;
            case 1:  W = Wv; D = Tv; break;
            case 2:  W = Wr; D = Tr; break;
            default: W = Wo; D = To; break;
        }
        const int by = ((bid >> 5) & 31) * 32, bx = (bid & 31) * 32;
        const int tx = threadIdx.x & 31, ty = threadIdx.x >> 5;
#pragma unroll
        for (int r = 0; r < 4; ++r)
            tile[ty + 8 * r][tx] = W[(size_t)(by + ty + 8 * r) * EE + bx + tx];
        __syncthreads();
#pragma unroll
        for (int r = 0; r < 4; ++r)
            D[(size_t)(bx + ty + 8 * r) * EE + by + tx] = f2bf(tile[tx][ty + 8 * r]);
    } else {
        const int gid  = (bid - 4096) * 256 + threadIdx.x;
        const int base = gid * 4;
        const int t = base >> 10;
        const int e = base & (EE - 1);
        float4 xv = *(const float4*)(x + base);
        float4 pv = (t > 0) ? *(const float4*)(x + base - EE) : *(const float4*)(sx + e);
        float4 mk = *(const float4*)(tmk + e);
        float4 mv = *(const float4*)(tmv + e);
        float4 mr = *(const float4*)(tmr + e);
        ushort4 ko, vo, ro;
        ko.x = f2bf(fmaf(mk.x, xv.x - pv.x, pv.x));
        ko.y = f2bf(fmaf(mk.y, xv.y - pv.y, pv.y));
        ko.z = f2bf(fmaf(mk.z, xv.z - pv.z, pv.z));
        ko.w = f2bf(fmaf(mk.w, xv.w - pv.w, pv.w));
        vo.x = f2bf(fmaf(mv.x, xv.x - pv.x, pv.x));
        vo.y = f2bf(fmaf(mv.y, xv.y - pv.y, pv.y));
        vo.z = f2bf(fmaf(mv.z, xv.z - pv.z, pv.z));
        vo.w = f2bf(fmaf(mv.w, xv.w - pv.w, pv.w));
        ro.x = f2bf(fmaf(mr.x, xv.x - pv.x, pv.x));
        ro.y = f2bf(fmaf(mr.y, xv.y - pv.y, pv.y));
        ro.z = f2bf(fmaf(mr.z, xv.z - pv.z, pv.z));
        ro.w = f2bf(fmaf(mr.w, xv.w - pv.w, pv.w));
        *(ushort4*)(kxb + base) = ko;
        *(ushort4*)(vxb + base) = vo;
        *(ushort4*)(rxb + base) = ro;
    }
}

// ---------------------------------------------------------------------------
// 128x128-tile bf16 GEMM, BK=64, 2-barrier K-loop (16 iters), XOR-swizzled
// LDS.  3 operand sets via blockIdx.z (z==2 -> sigmoid).  grid (64,8,3).
// PROVEN structure (~860 TF effective at round-0 clocks).  UNCHANGED: control.
// ---------------------------------------------------------------------------
__global__ __launch_bounds__(256, 4) void gemm_kvr3(
        const unsigned short* __restrict__ kxb, const unsigned short* __restrict__ vxb,
        const unsigned short* __restrict__ rxb,
        const unsigned short* __restrict__ Wkt, const unsigned short* __restrict__ Wvt,
        const unsigned short* __restrict__ Wrt,
        unsigned short* __restrict__ kf, unsigned short* __restrict__ vf,
        unsigned short* __restrict__ ry) {
    __shared__ __align__(16) unsigned short As[128 * 64];   // 16 KB
    __shared__ __align__(16) unsigned short Bs[128 * 64];   // 16 KB
    const int z = blockIdx.z;
    const unsigned short* A  = (z == 0) ? kxb : (z == 1) ? vxb : rxb;
    const unsigned short* Bt = (z == 0) ? Wkt : (z == 1) ? Wvt : Wrt;
    unsigned short* C        = (z == 0) ? kf  : (z == 1) ? vf  : ry;

    const int tid  = threadIdx.x;
    const int wave = tid >> 6, lane = tid & 63;
    const int wm = (wave >> 1) * 64, wn = (wave & 1) * 64;
    const int l15 = lane & 15, lq = lane >> 4;
    const int lrow = lane >> 3;                          // 8 lanes/row, 8 rows/instr
    const int lcolg = (((lane & 7) ^ lrow) & 7) * 8;     // swizzled global col group
    const int sw = l15 & 7;                              // read-side swizzle key
    const int bm = blockIdx.x * 128, bn = blockIdx.y * 128;

    f32x4 acc[4][4] = {};

    for (int kt = 0; kt < 1024; kt += 64) {
        __syncthreads();
#pragma unroll
        for (int p = 0; p < 4; ++p) {
            const int r0 = p * 32 + wave * 8;
            gload_lds16(A  + (size_t)(bm + r0 + lrow) * 1024 + kt + lcolg, &As[r0 * 64]);
            gload_lds16(Bt + (size_t)(bn + r0 + lrow) * 1024 + kt + lcolg, &Bs[r0 * 64]);
        }
        __syncthreads();
#pragma unroll
        for (int h = 0; h < 2; ++h) {
            bf16x8 af[4], bfr[4];
#pragma unroll
            for (int i = 0; i < 4; ++i) {
                const int g = ((h * 4 + lq) ^ sw) * 8;
                af[i]  = *(const bf16x8*)(&As[(wm + i * 16 + l15) * 64 + g]);
                bfr[i] = *(const bf16x8*)(&Bs[(wn + i * 16 + l15) * 64 + g]);
            }
#pragma unroll
            for (int i = 0; i < 4; ++i)
#pragma unroll
                for (int j = 0; j < 4; ++j)
                    acc[i][j] = __builtin_amdgcn_mfma_f32_16x16x32_bf16(af[i], bfr[j], acc[i][j], 0, 0, 0);
        }
    }

    const bool sig = (z == 2);
#pragma unroll
    for (int i = 0; i < 4; ++i)
#pragma unroll
        for (int j = 0; j < 4; ++j) {
            const int col = bn + wn + j * 16 + l15;
#pragma unroll
            for (int r = 0; r < 4; ++r) {
                const int row = bm + wm + i * 16 + lq * 4 + r;
                float val = acc[i][j][r];
                if (sig) val = 1.f / (1.f + __expf(-val));
                C[(size_t)row * 1024 + col] = f2bf(val);
            }
        }
}

// ---------------------------------------------------------------------------
// Wo GEMM: 128x128 tile, BK=64, XOR-swizzled LDS.  C f32 = A bf16 @ Bt^T + Res.
// grid (64,8) = 512 blocks.  UNCHANGED: control.
// ---------------------------------------------------------------------------
__global__ __launch_bounds__(256, 4) void gemm_wo(const unsigned short* __restrict__ A,
                                                  const unsigned short* __restrict__ Bt,
                                                  const float* __restrict__ Res,
                                                  float* __restrict__ C) {
    __shared__ __align__(16) unsigned short As[128 * 64];   // 16 KB
    __shared__ __align__(16) unsigned short Bs[128 * 64];   // 16 KB
    const int tid  = threadIdx.x;
    const int wave = tid >> 6, lane = tid & 63;
    const int wm = (wave >> 1) * 64, wn = (wave & 1) * 64;
    const int l15 = lane & 15, lq = lane >> 4;
    const int lrow = lane >> 3;
    const int lcolg = (((lane & 7) ^ lrow) & 7) * 8;
    const int sw = l15 & 7;
    const int bm = blockIdx.x * 128, bn = blockIdx.y * 128;

    f32x4 acc[4][4] = {};

    for (int kt = 0; kt < 1024; kt += 64) {
        __syncthreads();
#pragma unroll
        for (int p = 0; p < 4; ++p) {
            const int r0 = p * 32 + wave * 8;
            gload_lds16(A  + (size_t)(bm + r0 + lrow) * 1024 + kt + lcolg, &As[r0 * 64]);
            gload_lds16(Bt + (size_t)(bn + r0 + lrow) * 1024 + kt + lcolg, &Bs[r0 * 64]);
        }
        __syncthreads();
#pragma unroll
        for (int h = 0; h < 2; ++h) {
            bf16x8 af[4], bfr[4];
#pragma unroll
            for (int i = 0; i < 4; ++i) {
                const int g = ((h * 4 + lq) ^ sw) * 8;
                af[i]  = *(const bf16x8*)(&As[(wm + i * 16 + l15) * 64 + g]);
                bfr[i] = *(const bf16x8*)(&Bs[(wn + i * 16 + l15) * 64 + g]);
            }
#pragma unroll
            for (int i = 0; i < 4; ++i)
#pragma unroll
                for (int j = 0; j < 4; ++j)
                    acc[i][j] = __builtin_amdgcn_mfma_f32_16x16x32_bf16(af[i], bfr[j], acc[i][j], 0, 0, 0);
        }
    }

#pragma unroll
    for (int i = 0; i < 4; ++i)
#pragma unroll
        for (int j = 0; j < 4; ++j) {
            const int col = bn + wn + j * 16 + l15;
#pragma unroll
            for (int r = 0; r < 4; ++r) {
                const int row = bm + wm + i * 16 + lq * 4 + r;
                const size_t idx = (size_t)row * 1024 + col;
                C[idx] = acc[i][j][r] + Res[idx];
            }
        }
}

// ---------------------------------------------------------------------------
// FUSED WKV (big path): cooperative kernel, grid 512 x 256, 2 blocks/CU.
// NC=512 chunks of CL=16.  Block b <-> chunk b.
//  Phase A: chunk summary; k/v chunk parked in LDS (64 KB).
//  Phase B: per-block 2-channel scan (pair-combine + 256-wide Kogge-Stone).
//  Phase C: replay from LDS k/v (kills 32 MB re-read), ry in place.
// S layout [e*NC+c] (coalesced float2 reads in B); in layout [c*EE+e]
// (coalesced float4 reads in C).
// ---------------------------------------------------------------------------
__global__ __launch_bounds__(256, 2) void wkv_fused(
        const unsigned short* __restrict__ kf, const unsigned short* __restrict__ vf,
        const float* __restrict__ aa, const float* __restrict__ bb,
        const float* __restrict__ pp, const float* __restrict__ tf,
        const float* __restrict__ td, const float* __restrict__ x,
        unsigned short* __restrict__ ry,
        float* __restrict__ Sa, float* __restrict__ Sb, float* __restrict__ Sp,
        float* __restrict__ ina, float* __restrict__ inb, float* __restrict__ inp,
        float* __restrict__ outTail) {
    const int NC = 512, CL = 16;
    __shared__ __align__(16) unsigned short kL[16 * EE];   // 32 KB
    __shared__ __align__(16) unsigned short vL[16 * EE];   // 32 KB
    __shared__ float sA[256], sB[256], sP[256];            // 3 KB
    const int c = blockIdx.x, tid = threadIdx.x;
    const int e0 = tid * 4;

    // ---------------- Phase A: chunk summary + LDS park ----------------
    const float4 tdv = *(const float4*)(td + e0);
    float w4[4] = { -__expf(tdv.x), -__expf(tdv.y), -__expf(tdv.z), -__expf(tdv.w) };
    float sa[4] = {0.f, 0.f, 0.f, 0.f}, sb[4] = {0.f, 0.f, 0.f, 0.f};
    float sp[4] = {-1e30f, -1e30f, -1e30f, -1e30f};
    const size_t gbase = (size_t)c * CL * EE + e0;
#pragma unroll
    for (int i = 0; i < CL; ++i) {
        const ushort4 k4 = *(const ushort4*)(kf + gbase + (size_t)i * EE);
        const ushort4 v4 = *(const ushort4*)(vf + gbase + (size_t)i * EE);
        *(ushort4*)(kL + i * EE + e0) = k4;
        *(ushort4*)(vL + i * EE + e0) = v4;
        const unsigned short ks[4] = {k4.x, k4.y, k4.z, k4.w};
        const unsigned short vs[4] = {v4.x, v4.y, v4.z, v4.w};
        const float fi = (float)(CL - 1 - i);
#pragma unroll
        for (int j = 0; j < 4; ++j) {
            const float kk = b2f(ks[j]), vv = b2f(vs[j]);
            const float q  = fmaf(w4[j], fi, kk);
            const float p2 = fmaxf(sp[j], q);
            const float e1 = __expf(sp[j] - p2), e2 = __expf(q - p2);
            sa[j] = fmaf(e1, sa[j], e2 * vv);
            sb[j] = fmaf(e1, sb[j], e2);
            sp[j] = p2;
        }
    }
#pragma unroll
    for (int j = 0; j < 4; ++j) {
        Sa[(size_t)(e0 + j) * NC + c] = sa[j];
        Sb[(size_t)(e0 + j) * NC + c] = sb[j];
        Sp[(size_t)(e0 + j) * NC + c] = sp[j];
    }
    __threadfence();
    cg::this_grid().sync();

    // ---------------- Phase B: scan for channels 2c, 2c+1 ----------------
    for (int ch = 0; ch < 2; ++ch) {
        const int e = 2 * c + ch;
        const float w = -__expf(td[e]);
        // load pair (chunks 2*tid, 2*tid+1)
        const float2 a2 = *(const float2*)(Sa + (size_t)e * NC + 2 * tid);
        const float2 b2 = *(const float2*)(Sb + (size_t)e * NC + 2 * tid);
        const float2 p2 = *(const float2*)(Sp + (size_t)e * NC + 2 * tid);
        const float eA = a2.x, eB = b2.x, eP = p2.x;  // raw left-chunk summary
        // pair combine: left decayed by 1 chunk, merged with right
        float Pa, Pb, Pp;
        {
            const float pl = p2.x + w * (float)CL;
            const float pn = fmaxf(pl, p2.y);
            const float x1 = __expf(pl - pn), x2 = __expf(p2.y - pn);
            Pa = fmaf(x1, a2.x, x2 * a2.y);
            Pb = fmaf(x1, b2.x, x2 * b2.y);
            Pp = pn;
        }
        // Kogge-Stone over 256 pair-elements (each spans 2 chunks)
        for (int s = 1; s < 256; s <<= 1) {
            sA[tid] = Pa; sB[tid] = Pb; sP[tid] = Pp;
            __syncthreads();
            if (tid >= s) {
                const float pL = sP[tid - s] + w * (float)(CL * 2 * s);
                const float pn = fmaxf(pL, Pp);
                const float x1 = __expf(pL - pn), x2 = __expf(Pp - pn);
                Pa = fmaf(x1, sA[tid - s], x2 * Pa);
                Pb = fmaf(x1, sB[tid - s], x2 * Pb);
                Pp = pn;
            }
            __syncthreads();
        }
        sA[tid] = Pa; sB[tid] = Pb; sP[tid] = Pp;
        __syncthreads();

        const float a0 = aa[e], b0 = bb[e], p0 = pp[e];
        // incoming state for chunk c0 = 2*tid
        {
            const int cc = 2 * tid;
            float ea, eb, ep;
            if (tid == 0) { ea = a0; eb = b0; ep = p0; }
            else {
                const float aP = sA[tid - 1], bP = sB[tid - 1], pP = sP[tid - 1];
                const float p0d = p0 + w * (float)(cc * CL);
                const float pn  = fmaxf(p0d, pP);
                const float x1  = __expf(p0d - pn), x2 = __expf(pP - pn);
                ea = fmaf(x1, a0, x2 * aP);
                eb = fmaf(x1, b0, x2 * bP);
                ep = pn;
            }
            ina[(size_t)cc * EE + e] = ea;
            inb[(size_t)cc * EE + e] = eb;
            inp[(size_t)cc * EE + e] = ep;
        }
        // incoming state for chunk c1 = 2*tid+1: Q = incl[0..2*tid]
        {
            float qa, qb, qp;
            if (tid == 0) { qa = eA; qb = eB; qp = eP; }
            else {
                const float pL = sP[tid - 1] + w * (float)CL;
                const float pn = fmaxf(pL, eP);
                const float x1 = __expf(pL - pn), x2 = __expf(eP - pn);
                qa = fmaf(x1, sA[tid - 1], x2 * eA);
                qb = fmaf(x1, sB[tid - 1], x2 * eB);
                qp = pn;
            }
            const int cc = 2 * tid + 1;
            const float p0d = p0 + w * (float)(cc * CL);
            const float pn  = fmaxf(p0d, qp);
            const float x1  = __expf(p0d - pn), x2 = __expf(qp - pn);
            ina[(size_t)cc * EE + e] = fmaf(x1, a0, x2 * qa);
            inb[(size_t)cc * EE + e] = fmaf(x1, b0, x2 * qb);
            inp[(size_t)cc * EE + e] = pn;
        }
        if (tid == 255) {
            const float p0d = p0 + w * (float)TT;
            const float pn  = fmaxf(p0d, Pp);
            const float x1  = __expf(p0d - pn), x2 = __expf(Pp - pn);
            outTail[e]          = x[(size_t)(TT - 1) * EE + e];
            outTail[EE + e]     = fmaf(x1, a0, x2 * Pa);
            outTail[2 * EE + e] = fmaf(x1, b0, x2 * Pb);
            outTail[3 * EE + e] = pn;
        }
        __syncthreads();   // protect sA/sB/sP before next channel
    }
    __threadfence();
    cg::this_grid().sync();

    // ---------------- Phase C: replay from LDS ----------------
    const float4 tfv = *(const float4*)(tf + e0);
    const float u[4] = { tfv.x, tfv.y, tfv.z, tfv.w };
    float a[4], b[4], p[4];
    {
        const float4 av = *(const float4*)(ina + (size_t)c * EE + e0);
        const float4 bv = *(const float4*)(inb + (size_t)c * EE + e0);
        const float4 pv = *(const float4*)(inp + (size_t)c * EE + e0);
        a[0] = av.x; a[1] = av.y; a[2] = av.z; a[3] = av.w;
        b[0] = bv.x; b[1] = bv.y; b[2] = bv.z; b[3] = bv.w;
        p[0] = pv.x; p[1] = pv.y; p[2] = pv.z; p[3] = pv.w;
    }
#pragma unroll 4
    for (int i = 0; i < CL; ++i) {
        const ushort4 k4 = *(const ushort4*)(kL + i * EE + e0);
        const ushort4 v4 = *(const ushort4*)(vL + i * EE + e0);
        const ushort4 r4 = *(const ushort4*)(ry + gbase + (size_t)i * EE);
        const unsigned short ks[4] = {k4.x, k4.y, k4.z, k4.w};
        const unsigned short vs[4] = {v4.x, v4.y, v4.z, v4.w};
        const unsigned short rs[4] = {r4.x, r4.y, r4.z, r4.w};
        unsigned short os[4];
#pragma unroll
        for (int j = 0; j < 4; ++j) {
            const float kk = b2f(ks[j]), vv = b2f(vs[j]), rr = b2f(rs[j]);
            const float ww = u[j] + kk;
            const float pq = fmaxf(p[j], ww);
            const float e1 = __expf(p[j] - pq), e2 = __expf(ww - pq);
            const float wkv = fmaf(e1, a[j], e2 * vv) * __builtin_amdgcn_rcpf(fmaf(e1, b[j], e2));
            os[j] = f2bf(rr * wkv);
            const float ww2 = w4[j] + p[j];
            const float pz  = fmaxf(ww2, kk);
            const float e1b = __expf(ww2 - pz), e2b = __expf(kk - pz);
            a[j] = fmaf(e1b, a[j], e2b * vv);
            b[j] = fmaf(e1b, b[j], e2b);
            p[j] = pz;
        }
        ushort4 o4;
        o4.x = os[0]; o4.y = os[1]; o4.z = os[2]; o4.w = os[3];
        *(ushort4*)(ry + gbase + (size_t)i * EE) = o4;
    }
}

// ---------------------------------------------------------------------------
// SMALL path kernels (proven fallback, unchanged).
// ---------------------------------------------------------------------------
template <int NC>
__global__ void wkv_pass_a(const unsigned short* __restrict__ k,
                           const unsigned short* __restrict__ v,
                           const float* __restrict__ td,
                           float* __restrict__ Sa, float* __restrict__ Sb, float* __restrict__ Sp) {
    const int CL = TT / NC;
    const int gid = blockIdx.x * 256 + threadIdx.x;
    const int c  = gid >> 8;
    const int e0 = (gid & 255) * 4;
    const float4 tdv = *(const float4*)(td + e0);
    float w[4] = { -__expf(tdv.x), -__expf(tdv.y), -__expf(tdv.z), -__expf(tdv.w) };
    float sa[4] = {0.f, 0.f, 0.f, 0.f}, sb[4] = {0.f, 0.f, 0.f, 0.f};
    float sp[4] = {-1e30f, -1e30f, -1e30f, -1e30f};
    const size_t base = (size_t)c * CL * EE + e0;
#pragma unroll
    for (int i = 0; i < CL; ++i) {
        const ushort4 k4 = *(const ushort4*)(k + base + (size_t)i * EE);
        const ushort4 v4 = *(const ushort4*)(v + base + (size_t)i * EE);
        const unsigned short ks[4] = {k4.x, k4.y, k4.z, k4.w};
        const unsigned short vs[4] = {v4.x, v4.y, v4.z, v4.w};
        const float fi = (float)(CL - 1 - i);
#pragma unroll
        for (int j = 0; j < 4; ++j) {
            const float kk = b2f(ks[j]), vv = b2f(vs[j]);
            const float q  = fmaf(w[j], fi, kk);
            const float p2 = fmaxf(sp[j], q);
            const float e1 = __expf(sp[j] - p2), e2 = __expf(q - p2);
            sa[j] = fmaf(e1, sa[j], e2 * vv);
            sb[j] = fmaf(e1, sb[j], e2);
            sp[j] = p2;
        }
    }
#pragma unroll
    for (int j = 0; j < 4; ++j) {
        Sa[c * EE + e0 + j] = sa[j];
        Sb[c * EE + e0 + j] = sb[j];
        Sp[c * EE + e0 + j] = sp[j];
    }
}

__global__ void wkv_pass_b_small(const float* __restrict__ aa, const float* __restrict__ bb,
                                 const float* __restrict__ pp, const float* __restrict__ td,
                                 const float* __restrict__ x,
                                 const float* __restrict__ Sa, const float* __restrict__ Sb,
                                 const float* __restrict__ Sp,
                                 float* __restrict__ ina, float* __restrict__ inb,
                                 float* __restrict__ inp, float* __restrict__ outTail) {
    const int NC = 128, CL = TT / NC;
    const int e = blockIdx.x * 256 + threadIdx.x;
    const float w  = -__expf(td[e]);
    const float wL = w * (float)CL;
    float a = aa[e], b = bb[e], p = pp[e];
    for (int c = 0; c < NC; ++c) {
        ina[e * NC + c] = a; inb[e * NC + c] = b; inp[e * NC + c] = p;
        const int idx = c * EE + e;
        const float sa = Sa[idx], sb = Sb[idx], sp = Sp[idx];
        const float pw = p + wL;
        const float p2 = fmaxf(pw, sp);
        const float e1 = __expf(pw - p2), e2 = __expf(sp - p2);
        a = fmaf(e1, a, e2 * sa);
        b = fmaf(e1, b, e2 * sb);
        p = p2;
    }
    outTail[e]          = x[(size_t)(TT - 1) * EE + e];
    outTail[EE + e]     = a;
    outTail[2 * EE + e] = b;
    outTail[3 * EE + e] = p;
}

template <int NC>
__global__ void wkv_pass_c(const unsigned short* __restrict__ k,
                           const unsigned short* __restrict__ v,
                           const float* __restrict__ tf, const float* __restrict__ td,
                           const float* __restrict__ ina, const float* __restrict__ inb,
                           const float* __restrict__ inp,
                           unsigned short* ry) {
    const int CL = TT / NC;
    const int gid = blockIdx.x * 256 + threadIdx.x;
    const int c  = gid >> 8;
    const int e0 = (gid & 255) * 4;
    const float4 tdv = *(const float4*)(td + e0);
    const float4 tfv = *(const float4*)(tf + e0);
    float w[4] = { -__expf(tdv.x), -__expf(tdv.y), -__expf(tdv.z), -__expf(tdv.w) };
    float u[4] = { tfv.x, tfv.y, tfv.z, tfv.w };
    float a[4], b[4], p[4];
#pragma unroll
    for (int j = 0; j < 4; ++j) {
        a[j] = ina[(e0 + j) * NC + c];
        b[j] = inb[(e0 + j) * NC + c];
        p[j] = inp[(e0 + j) * NC + c];
    }
    const size_t base = (size_t)c * CL * EE + e0;
#pragma unroll 4
    for (int i = 0; i < CL; ++i) {
        const size_t idx = base + (size_t)i * EE;
        const ushort4 k4 = *(const ushort4*)(k + idx);
        const ushort4 v4 = *(const ushort4*)(v + idx);
        const ushort4 r4 = *(const ushort4*)(ry + idx);
        const unsigned short ks[4] = {k4.x, k4.y, k4.z, k4.w};
        const unsigned short vs[4] = {v4.x, v4.y, v4.z, v4.w};
        const unsigned short rs[4] = {r4.x, r4.y, r4.z, r4.w};
        unsigned short os[4];
#pragma unroll
        for (int j = 0; j < 4; ++j) {
            const float kk = b2f(ks[j]), vv = b2f(vs[j]), rr = b2f(rs[j]);
            const float ww = u[j] + kk;
            const float pq = fmaxf(p[j], ww);
            const float e1 = __expf(p[j] - pq), e2 = __expf(ww - pq);
            const float wkv = fmaf(e1, a[j], e2 * vv) * __builtin_amdgcn_rcpf(fmaf(e1, b[j], e2));
            os[j] = f2bf(rr * wkv);
            const float ww2 = w[j] + p[j];
            const float p2  = fmaxf(ww2, kk);
            const float e1b = __expf(ww2 - p2), e2b = __expf(kk - p2);
            a[j] = fmaf(e1b, a[j], e2b * vv);
            b[j] = fmaf(e1b, b[j], e2b);
            p[j] = p2;
        }
        ushort4 o4;
        o4.x = os[0]; o4.y = os[1]; o4.z = os[2]; o4.w = os[3];
        *(ushort4*)(ry + idx) = o4;
    }
}

__global__ __launch_bounds__(256, 4) void gemm_kvr(
        const float* __restrict__ X, const float* __restrict__ SX,
        const float* __restrict__ tmk, const float* __restrict__ tmv,
        const float* __restrict__ tmr,
        const unsigned short* __restrict__ Wkt, const unsigned short* __restrict__ Wvt,
        const unsigned short* __restrict__ Wrt,
        unsigned short* __restrict__ outK, unsigned short* __restrict__ outV,
        unsigned short* __restrict__ outR) {
    __shared__ __align__(16) unsigned short As[128 * LDSK];
    __shared__ __align__(16) unsigned short Bs[128 * LDSK];
    const int z = blockIdx.z;
    const float* TM = (z == 0) ? tmk : (z == 1) ? tmv : tmr;
    const unsigned short* Bt = (z == 0) ? Wkt : (z == 1) ? Wvt : Wrt;
    unsigned short* Cout = (z == 0) ? outK : (z == 1) ? outV : outR;

    const int tid  = threadIdx.x;
    const int wave = tid >> 6, lane = tid & 63;
    const int wm = (wave >> 1) * 64, wn = (wave & 1) * 64;
    const int l15 = lane & 15, lq = lane >> 4;
    const int bm = blockIdx.x * 128, bn = blockIdx.y * 128;

    f32x4 acc[4][4] = {};

    for (int kt = 0; kt < 1024; kt += 32) {
        __syncthreads();
#pragma unroll
        for (int p = 0; p < 2; ++p) {
            const int li  = p * 256 + tid;
            const int row = li >> 2, q = li & 3;
            const int e0  = kt + q * 8;
            {
                const int t = bm + row;
                const float* xr = X + (size_t)t * EE + e0;
                const float* pr = (t > 0) ? (X + (size_t)(t - 1) * EE + e0) : (SX + e0);
                float4 xa = *(const float4*)xr, xb = *(const float4*)(xr + 4);
                float4 pa = *(const float4*)pr, pb = *(const float4*)(pr + 4);
                float4 ma = *(const float4*)(TM + e0), mb = *(const float4*)(TM + e0 + 4);
                ushort4 lo, hi;
                lo.x = f2bf(fmaf(ma.x, xa.x - pa.x, pa.x));
                lo.y = f2bf(fmaf(ma.y, xa.y - pa.y, pa.y));
                lo.z = f2bf(fmaf(ma.z, xa.z - pa.z, pa.z));
                lo.w = f2bf(fmaf(ma.w, xa.w - pa.w, pa.w));
                hi.x = f2bf(fmaf(mb.x, xb.x - pb.x, pb.x));
                hi.y = f2bf(fmaf(mb.y, xb.y - pb.y, pb.y));
                hi.z = f2bf(fmaf(mb.z, xb.z - pb.z, pb.z));
                hi.w = f2bf(fmaf(mb.w, xb.w - pb.w, pb.w));
                *(ushort4*)(&As[row * LDSK + q * 8])     = lo;
                *(ushort4*)(&As[row * LDSK + q * 8 + 4]) = hi;
            }
            *(uint4*)(&Bs[row * LDSK + q * 8]) =
                *(const uint4*)(Bt + (size_t)(bn + row) * 1024 + e0);
        }
        __syncthreads();
        bf16x8 af[4], bfr[4];
#pragma unroll
        for (int i = 0; i < 4; ++i) {
            af[i]  = *(const bf16x8*)(&As[(wm + i * 16 + l15) * LDSK + lq * 8]);
            bfr[i] = *(const bf16x8*)(&Bs[(wn + i * 16 + l15) * LDSK + lq * 8]);
        }
#pragma unroll
        for (int i = 0; i < 4; ++i)
#pragma unroll
            for (int j = 0; j < 4; ++j)
                acc[i][j] = __builtin_amdgcn_mfma_f32_16x16x32_bf16(af[i], bfr[j], acc[i][j], 0, 0, 0);
    }

    const bool sig = (z == 2);
#pragma unroll
    for (int i = 0; i < 4; ++i)
#pragma unroll
        for (int j = 0; j < 4; ++j) {
            const int col = bn + wn + j * 16 + l15;
#pragma unroll
            for (int r = 0; r < 4; ++r) {
                const int row = bm + wm + i * 16 + lq * 4 + r;
                float val = acc[i][j][r];
                if (sig) val = 1.f / (1.f + __expf(-val));
                Cout[(size_t)row * 1024 + col] = f2bf(val);
            }
        }
}

// ---------------------------------------------------------------------------
extern "C" void kernel_launch(void* const* d_in, const int* in_sizes, int n_in,
                              void* d_out, int out_size, void* d_ws, size_t ws_size,
                              hipStream_t stream) {
    const float* x   = (const float*)d_in[0];
    const float* sx  = (const float*)d_in[1];
    const float* aa  = (const float*)d_in[2];
    const float* bb  = (const float*)d_in[3];
    const float* pp  = (const float*)d_in[4];
    const float* tf  = (const float*)d_in[5];
    const float* td  = (const float*)d_in[6];
    const float* tmk = (const float*)d_in[7];
    const float* tmv = (const float*)d_in[8];
    const float* tmr = (const float*)d_in[9];
    const float* Wk  = (const float*)d_in[10];
    const float* Wv  = (const float*)d_in[11];
    const float* Wr  = (const float*)d_in[12];
    const float* Wo  = (const float*)d_in[13];
    float* out = (float*)d_out;

    char* ws = (char*)d_ws;
    const size_t MB = 1ull << 20;

    unsigned short* Wkt = (unsigned short*)(ws + 0 * MB);   // 2 MB each
    unsigned short* Wvt = (unsigned short*)(ws + 2 * MB);
    unsigned short* Wrt = (unsigned short*)(ws + 4 * MB);
    unsigned short* Wot = (unsigned short*)(ws + 6 * MB);

    if (ws_size >= 75 * MB) {
        // ws: [0:8] Wt | [8:24] rxb (scan bufs overlay after kvr3) |
        //     [24:40] kf | [40:56] ry | [56:72] vf
        unsigned short* rxb = (unsigned short*)(ws + 8 * MB);
        unsigned short* kf  = (unsigned short*)(ws + 24 * MB);
        unsigned short* ry  = (unsigned short*)(ws + 40 * MB);
        unsigned short* vf  = (unsigned short*)(ws + 56 * MB);
        // scan buffers (NC=512): 6 x 2 MB, overlaying the dead rxb region [8:20]
        float* Sa  = (float*)(ws + 8  * MB);
        float* Sb  = (float*)(ws + 10 * MB);
        float* Sp  = (float*)(ws + 12 * MB);
        float* ina = (float*)(ws + 14 * MB);
        float* inb = (float*)(ws + 16 * MB);
        float* inp = (float*)(ws + 18 * MB);
        unsigned short* kxb = (unsigned short*)d_out;                   // d_out scratch
        unsigned short* vxb = (unsigned short*)d_out + (size_t)TT * EE;
        float* outTail = out + (size_t)TT * EE;

        prep_kernel<<<12288, 256, 0, stream>>>(Wk, Wv, Wr, Wo, Wkt, Wvt, Wrt, Wot,
                                               x, sx, tmk, tmv, tmr, kxb, vxb, rxb);
        gemm_kvr3<<<dim3(64, 8, 3), 256, 0, stream>>>(kxb, vxb, rxb, Wkt, Wvt, Wrt,
                                                      kf, vf, ry);
        {
            const unsigned short* kfc = kf;
            const unsigned short* vfc = vf;
            void* args[] = {
                (void*)&kfc, (void*)&vfc, (void*)&aa, (void*)&bb, (void*)&pp,
                (void*)&tf, (void*)&td, (void*)&x, (void*)&ry,
                (void*)&Sa, (void*)&Sb, (void*)&Sp,
                (void*)&ina, (void*)&inb, (void*)&inp, (void*)&outTail
            };
            hipLaunchCooperativeKernel((const void*)wkv_fused, dim3(512), dim3(256),
                                       args, 0, stream);
        }
        gemm_wo<<<dim3(64, 8), 256, 0, stream>>>(ry, Wot, x, out);
    } else {
        // 27 MB proven fallback (NC=128)
        unsigned short* ry = (unsigned short*)(ws + 8 * MB);
        char* scan = ws + 24 * MB;
        const size_t QK = (size_t)128 * EE * sizeof(float);  // 512 KB
        float* Sa  = (float*)(scan);
        float* Sb  = (float*)(scan + QK);
        float* Sp  = (float*)(scan + 2 * QK);
        float* ina = (float*)(scan + 3 * QK);
        float* inb = (float*)(scan + 4 * QK);
        float* inp = (float*)(scan + 5 * QK);
        unsigned short* kf = (unsigned short*)d_out;
        unsigned short* vf = (unsigned short*)d_out + (size_t)TT * EE;

        wt_kernel<<<dim3(32, 32, 4), dim3(32, 8), 0, stream>>>(Wk, Wv, Wr, Wo, Wkt, Wvt, Wrt, Wot);
        gemm_kvr<<<dim3(64, 8, 3), 256, 0, stream>>>(x, sx, tmk, tmv, tmr,
                                                     Wkt, Wvt, Wrt, kf, vf, ry);
        wkv_pass_a<128><<<128, 256, 0, stream>>>(kf, vf, td, Sa, Sb, Sp);
        wkv_pass_b_small<<<4, 256, 0, stream>>>(aa, bb, pp, td, x, Sa, Sb, Sp,
                                                ina, inb, inp, out + (size_t)TT * EE);
        wkv_pass_c<128><<<128, 256, 0, stream>>>(kf, vf, tf, td,
                                                 ina, inb, inp, ry);
        gemm_wo<<<dim3(64, 8), 256, 0, stream>>>(ry, Wot, x, out);
    }
}

// Round 4
// 272.298 us; speedup vs baseline: 1.9514x; 1.9514x over previous
//
#include <hip/hip_runtime.h>
#include <cstdint>
#include <cstddef>

typedef __bf16 bf16x8 __attribute__((ext_vector_type(8)));
typedef float  f32x4  __attribute__((ext_vector_type(4)));
typedef unsigned short u16x8 __attribute__((ext_vector_type(8)));

#define TT 8192
#define EE 1024
#define LDSK 40    // small-path padded LDS stride (shorts)

__device__ __forceinline__ unsigned short f2bf(float f) {
    union { float f; unsigned int u; } v; v.f = f;
    unsigned int r = v.u + 0x7FFFu + ((v.u >> 16) & 1u);
    return (unsigned short)(r >> 16);
}
__device__ __forceinline__ float b2f(unsigned int h) {
    union { unsigned int u; float f; } v; v.u = h << 16; return v.f;
}
__device__ __forceinline__ void gload_lds16(const void* g, void* l) {
    __builtin_amdgcn_global_load_lds((__attribute__((address_space(1))) void*)g,
                                     (__attribute__((address_space(3))) void*)l, 16, 0, 0);
}

// ---------------------------------------------------------------------------
// Standalone W transpose (small path). grid (32,32,4), block (32,8).
// ---------------------------------------------------------------------------
__global__ void wt_kernel(const float* __restrict__ Wk, const float* __restrict__ Wv,
                          const float* __restrict__ Wr, const float* __restrict__ Wo,
                          unsigned short* __restrict__ Tk, unsigned short* __restrict__ Tv,
                          unsigned short* __restrict__ Tr, unsigned short* __restrict__ To) {
    __shared__ float tile[32][33];
    const float* W; unsigned short* D;
    switch (blockIdx.z) {
        case 0:  W = Wk; D = Tk; break;
        case 1:  W = Wv; D = Tv; break;
        case 2:  W = Wr; D = Tr; break;
        default: W = Wo; D = To; break;
    }
    const int bx = blockIdx.x * 32, by = blockIdx.y * 32;
    const int tx = threadIdx.x, ty = threadIdx.y;
#pragma unroll
    for (int r = 0; r < 4; ++r)
        tile[ty + 8 * r][tx] = W[(size_t)(by + ty + 8 * r) * EE + bx + tx];
    __syncthreads();
#pragma unroll
    for (int r = 0; r < 4; ++r)
        D[(size_t)(bx + ty + 8 * r) * EE + by + tx] = f2bf(tile[tx][ty + 8 * r]);
}

// ---------------------------------------------------------------------------
// Fused prep: blocks [0,4096) transpose 4 Ws; blocks [4096,12288) token-shift
// mix -> bf16 kx/vx/rx.  1D grid 12288, block 256.
// ---------------------------------------------------------------------------
__global__ void prep_kernel(const float* __restrict__ Wk, const float* __restrict__ Wv,
                            const float* __restrict__ Wr, const float* __restrict__ Wo,
                            unsigned short* __restrict__ Tk, unsigned short* __restrict__ Tv,
                            unsigned short* __restrict__ Tr, unsigned short* __restrict__ To,
                            const float* __restrict__ x, const float* __restrict__ sx,
                            const float* __restrict__ tmk, const float* __restrict__ tmv,
                            const float* __restrict__ tmr,
                            unsigned short* __restrict__ kxb, unsigned short* __restrict__ vxb,
                            unsigned short* __restrict__ rxb) {
    const int bid = blockIdx.x;
    if (bid < 4096) {
        __shared__ float tile[32][33];
        const int z = bid >> 10;
        const float* W; unsigned short* D;
        switch (z) {
            case 0:  W = Wk; D = Tk; break;
            case 1:  W = Wv; D = Tv; break;
            case 2:  W = Wr; D = Tr; break;
            default: W = Wo; D = To; break;
        }
        const int by = ((bid >> 5) & 31) * 32, bx = (bid & 31) * 32;
        const int tx = threadIdx.x & 31, ty = threadIdx.x >> 5;
#pragma unroll
        for (int r = 0; r < 4; ++r)
            tile[ty + 8 * r][tx] = W[(size_t)(by + ty + 8 * r) * EE + bx + tx];
        __syncthreads();
#pragma unroll
        for (int r = 0; r < 4; ++r)
            D[(size_t)(bx + ty + 8 * r) * EE + by + tx] = f2bf(tile[tx][ty + 8 * r]);
    } else {
        const int gid  = (bid - 4096) * 256 + threadIdx.x;
        const int base = gid * 4;
        const int t = base >> 10;
        const int e = base & (EE - 1);
        float4 xv = *(const float4*)(x + base);
        float4 pv = (t > 0) ? *(const float4*)(x + base - EE) : *(const float4*)(sx + e);
        float4 mk = *(const float4*)(tmk + e);
        float4 mv = *(const float4*)(tmv + e);
        float4 mr = *(const float4*)(tmr + e);
        ushort4 ko, vo, ro;
        ko.x = f2bf(fmaf(mk.x, xv.x - pv.x, pv.x));
        ko.y = f2bf(fmaf(mk.y, xv.y - pv.y, pv.y));
        ko.z = f2bf(fmaf(mk.z, xv.z - pv.z, pv.z));
        ko.w = f2bf(fmaf(mk.w, xv.w - pv.w, pv.w));
        vo.x = f2bf(fmaf(mv.x, xv.x - pv.x, pv.x));
        vo.y = f2bf(fmaf(mv.y, xv.y - pv.y, pv.y));
        vo.z = f2bf(fmaf(mv.z, xv.z - pv.z, pv.z));
        vo.w = f2bf(fmaf(mv.w, xv.w - pv.w, pv.w));
        ro.x = f2bf(fmaf(mr.x, xv.x - pv.x, pv.x));
        ro.y = f2bf(fmaf(mr.y, xv.y - pv.y, pv.y));
        ro.z = f2bf(fmaf(mr.z, xv.z - pv.z, pv.z));
        ro.w = f2bf(fmaf(mr.w, xv.w - pv.w, pv.w));
        *(ushort4*)(kxb + base) = ko;
        *(ushort4*)(vxb + base) = vo;
        *(ushort4*)(rxb + base) = ro;
    }
}

// ---------------------------------------------------------------------------
// 128x128-tile bf16 GEMM, BK=64, 2-barrier K-loop (16 iters), XOR-swizzled
// LDS.  3 operand sets via blockIdx.z (z==2 -> sigmoid).  grid (64,8,3).
// PROVEN structure (~860 TF effective at healthy clocks).  UNCHANGED: control.
// ---------------------------------------------------------------------------
__global__ __launch_bounds__(256, 4) void gemm_kvr3(
        const unsigned short* __restrict__ kxb, const unsigned short* __restrict__ vxb,
        const unsigned short* __restrict__ rxb,
        const unsigned short* __restrict__ Wkt, const unsigned short* __restrict__ Wvt,
        const unsigned short* __restrict__ Wrt,
        unsigned short* __restrict__ kf, unsigned short* __restrict__ vf,
        unsigned short* __restrict__ ry) {
    __shared__ __align__(16) unsigned short As[128 * 64];   // 16 KB
    __shared__ __align__(16) unsigned short Bs[128 * 64];   // 16 KB
    const int z = blockIdx.z;
    const unsigned short* A  = (z == 0) ? kxb : (z == 1) ? vxb : rxb;
    const unsigned short* Bt = (z == 0) ? Wkt : (z == 1) ? Wvt : Wrt;
    unsigned short* C        = (z == 0) ? kf  : (z == 1) ? vf  : ry;

    const int tid  = threadIdx.x;
    const int wave = tid >> 6, lane = tid & 63;
    const int wm = (wave >> 1) * 64, wn = (wave & 1) * 64;
    const int l15 = lane & 15, lq = lane >> 4;
    const int lrow = lane >> 3;                          // 8 lanes/row, 8 rows/instr
    const int lcolg = (((lane & 7) ^ lrow) & 7) * 8;     // swizzled global col group
    const int sw = l15 & 7;                              // read-side swizzle key
    const int bm = blockIdx.x * 128, bn = blockIdx.y * 128;

    f32x4 acc[4][4] = {};

    for (int kt = 0; kt < 1024; kt += 64) {
        __syncthreads();
#pragma unroll
        for (int p = 0; p < 4; ++p) {
            const int r0 = p * 32 + wave * 8;
            gload_lds16(A  + (size_t)(bm + r0 + lrow) * 1024 + kt + lcolg, &As[r0 * 64]);
            gload_lds16(Bt + (size_t)(bn + r0 + lrow) * 1024 + kt + lcolg, &Bs[r0 * 64]);
        }
        __syncthreads();
#pragma unroll
        for (int h = 0; h < 2; ++h) {
            bf16x8 af[4], bfr[4];
#pragma unroll
            for (int i = 0; i < 4; ++i) {
                const int g = ((h * 4 + lq) ^ sw) * 8;
                af[i]  = *(const bf16x8*)(&As[(wm + i * 16 + l15) * 64 + g]);
                bfr[i] = *(const bf16x8*)(&Bs[(wn + i * 16 + l15) * 64 + g]);
            }
#pragma unroll
            for (int i = 0; i < 4; ++i)
#pragma unroll
                for (int j = 0; j < 4; ++j)
                    acc[i][j] = __builtin_amdgcn_mfma_f32_16x16x32_bf16(af[i], bfr[j], acc[i][j], 0, 0, 0);
        }
    }

    const bool sig = (z == 2);
#pragma unroll
    for (int i = 0; i < 4; ++i)
#pragma unroll
        for (int j = 0; j < 4; ++j) {
            const int col = bn + wn + j * 16 + l15;
#pragma unroll
            for (int r = 0; r < 4; ++r) {
                const int row = bm + wm + i * 16 + lq * 4 + r;
                float val = acc[i][j][r];
                if (sig) val = 1.f / (1.f + __expf(-val));
                C[(size_t)row * 1024 + col] = f2bf(val);
            }
        }
}

// ---------------------------------------------------------------------------
// Wo GEMM: 128x128 tile, BK=64, XOR-swizzled LDS.  C f32 = A bf16 @ Bt^T + Res.
// grid (64,8) = 512 blocks.  UNCHANGED: control.
// ---------------------------------------------------------------------------
__global__ __launch_bounds__(256, 4) void gemm_wo(const unsigned short* __restrict__ A,
                                                  const unsigned short* __restrict__ Bt,
                                                  const float* __restrict__ Res,
                                                  float* __restrict__ C) {
    __shared__ __align__(16) unsigned short As[128 * 64];   // 16 KB
    __shared__ __align__(16) unsigned short Bs[128 * 64];   // 16 KB
    const int tid  = threadIdx.x;
    const int wave = tid >> 6, lane = tid & 63;
    const int wm = (wave >> 1) * 64, wn = (wave & 1) * 64;
    const int l15 = lane & 15, lq = lane >> 4;
    const int lrow = lane >> 3;
    const int lcolg = (((lane & 7) ^ lrow) & 7) * 8;
    const int sw = l15 & 7;
    const int bm = blockIdx.x * 128, bn = blockIdx.y * 128;

    f32x4 acc[4][4] = {};

    for (int kt = 0; kt < 1024; kt += 64) {
        __syncthreads();
#pragma unroll
        for (int p = 0; p < 4; ++p) {
            const int r0 = p * 32 + wave * 8;
            gload_lds16(A  + (size_t)(bm + r0 + lrow) * 1024 + kt + lcolg, &As[r0 * 64]);
            gload_lds16(Bt + (size_t)(bn + r0 + lrow) * 1024 + kt + lcolg, &Bs[r0 * 64]);
        }
        __syncthreads();
#pragma unroll
        for (int h = 0; h < 2; ++h) {
            bf16x8 af[4], bfr[4];
#pragma unroll
            for (int i = 0; i < 4; ++i) {
                const int g = ((h * 4 + lq) ^ sw) * 8;
                af[i]  = *(const bf16x8*)(&As[(wm + i * 16 + l15) * 64 + g]);
                bfr[i] = *(const bf16x8*)(&Bs[(wn + i * 16 + l15) * 64 + g]);
            }
#pragma unroll
            for (int i = 0; i < 4; ++i)
#pragma unroll
                for (int j = 0; j < 4; ++j)
                    acc[i][j] = __builtin_amdgcn_mfma_f32_16x16x32_bf16(af[i], bfr[j], acc[i][j], 0, 0, 0);
        }
    }

#pragma unroll
    for (int i = 0; i < 4; ++i)
#pragma unroll
        for (int j = 0; j < 4; ++j) {
            const int col = bn + wn + j * 16 + l15;
#pragma unroll
            for (int r = 0; r < 4; ++r) {
                const int row = bm + wm + i * 16 + lq * 4 + r;
                const size_t idx = (size_t)row * 1024 + col;
                C[idx] = acc[i][j][r] + Res[idx];
            }
        }
}

// ---------------------------------------------------------------------------
// WKV pass A: per (chunk, channel-oct) stabilized local summary.
// Vec8 over e (u16x8 = 16 B/lane loads; wave reads 1 KB contiguous).
// grid NC*EE/(8*256) = NC/2 blocks x 256 threads.
// ---------------------------------------------------------------------------
template <int NC>
__global__ void wkv_pass_a(const unsigned short* __restrict__ k,
                           const unsigned short* __restrict__ v,
                           const float* __restrict__ td,
                           float* __restrict__ Sa, float* __restrict__ Sb,
                           float* __restrict__ Sp) {
    const int CL = TT / NC;
    const int gid = blockIdx.x * 256 + threadIdx.x;
    const int c  = gid >> 7;             // EE/8 = 128 octs per chunk
    const int e0 = (gid & 127) * 8;
    const float4 td0 = *(const float4*)(td + e0);
    const float4 td1 = *(const float4*)(td + e0 + 4);
    float w[8] = { -__expf(td0.x), -__expf(td0.y), -__expf(td0.z), -__expf(td0.w),
                   -__expf(td1.x), -__expf(td1.y), -__expf(td1.z), -__expf(td1.w) };
    float sa[8], sb[8], sp[8];
#pragma unroll
    for (int j = 0; j < 8; ++j) { sa[j] = 0.f; sb[j] = 0.f; sp[j] = -1e30f; }
    const size_t base = (size_t)c * CL * EE + e0;
#pragma unroll
    for (int i = 0; i < CL; ++i) {
        const u16x8 k8 = *(const u16x8*)(k + base + (size_t)i * EE);
        const u16x8 v8 = *(const u16x8*)(v + base + (size_t)i * EE);
        const float fi = (float)(CL - 1 - i);
#pragma unroll
        for (int j = 0; j < 8; ++j) {
            const float kk = b2f((unsigned short)k8[j]), vv = b2f((unsigned short)v8[j]);
            const float q  = fmaf(w[j], fi, kk);
            const float p2 = fmaxf(sp[j], q);
            const float e1 = __expf(sp[j] - p2), e2 = __expf(q - p2);
            sa[j] = fmaf(e1, sa[j], e2 * vv);
            sb[j] = fmaf(e1, sb[j], e2);
            sp[j] = p2;
        }
    }
    float4 o;
    o.x = sa[0]; o.y = sa[1]; o.z = sa[2]; o.w = sa[3];
    *(float4*)(Sa + c * EE + e0) = o;
    o.x = sa[4]; o.y = sa[5]; o.z = sa[6]; o.w = sa[7];
    *(float4*)(Sa + c * EE + e0 + 4) = o;
    o.x = sb[0]; o.y = sb[1]; o.z = sb[2]; o.w = sb[3];
    *(float4*)(Sb + c * EE + e0) = o;
    o.x = sb[4]; o.y = sb[5]; o.z = sb[6]; o.w = sb[7];
    *(float4*)(Sb + c * EE + e0 + 4) = o;
    o.x = sp[0]; o.y = sp[1]; o.z = sp[2]; o.w = sp[3];
    *(float4*)(Sp + c * EE + e0) = o;
    o.x = sp[4]; o.y = sp[5]; o.z = sp[6]; o.w = sp[7];
    *(float4*)(Sp + c * EE + e0 + 4) = o;
}

// ---------------------------------------------------------------------------
// WKV pass B (parallel): Kogge-Stone scan over NC chunk summaries per
// channel.  grid EE blocks x NC threads.  ina/inb/inp layout: [e*NC + c].
// ---------------------------------------------------------------------------
template <int NC>
__global__ void wkv_pass_b_par(const float* __restrict__ aa, const float* __restrict__ bb,
                               const float* __restrict__ pp, const float* __restrict__ td,
                               const float* __restrict__ x,
                               const float* __restrict__ Sa, const float* __restrict__ Sb,
                               const float* __restrict__ Sp,
                               float* __restrict__ ina, float* __restrict__ inb,
                               float* __restrict__ inp, float* __restrict__ outTail) {
    const int CL = TT / NC;
    const int e = blockIdx.x, c = threadIdx.x;
    __shared__ float sA[NC], sB[NC], sP[NC];
    const float w = -__expf(td[e]);

    float a = Sa[c * EE + e], b = Sb[c * EE + e], p = Sp[c * EE + e];

    for (int s = 1; s < NC; s <<= 1) {
        sA[c] = a; sB[c] = b; sP[c] = p;
        __syncthreads();
        if (c >= s) {
            const float myLen = (float)(CL * min(c + 1, s));
            const float aL = sA[c - s], bL = sB[c - s], pL = sP[c - s];
            const float pLd = pL + w * myLen;
            const float pn  = fmaxf(pLd, p);
            const float e1  = __expf(pLd - pn), e2 = __expf(p - pn);
            a = fmaf(e1, aL, e2 * a);
            b = fmaf(e1, bL, e2 * b);
            p = pn;
        }
        __syncthreads();
    }

    sA[c] = a; sB[c] = b; sP[c] = p;
    __syncthreads();

    const float a0 = aa[e], b0 = bb[e], p0 = pp[e];
    float ea, eb, ep;
    if (c == 0) { ea = a0; eb = b0; ep = p0; }
    else {
        const float aL = sA[c - 1], bL = sB[c - 1], pL = sP[c - 1];
        const float p0d = p0 + w * (float)(c * CL);
        const float pn  = fmaxf(p0d, pL);
        const float e1  = __expf(p0d - pn), e2 = __expf(pL - pn);
        ea = fmaf(e1, a0, e2 * aL);
        eb = fmaf(e1, b0, e2 * bL);
        ep = pn;
    }
    ina[e * NC + c] = ea; inb[e * NC + c] = eb; inp[e * NC + c] = ep;

    if (c == NC - 1) {
        const float p0d = p0 + w * (float)TT;
        const float pn  = fmaxf(p0d, p);
        const float e1  = __expf(p0d - pn), e2 = __expf(p - pn);
        outTail[e]          = x[(size_t)(TT - 1) * EE + e];
        outTail[EE + e]     = fmaf(e1, a0, e2 * a);
        outTail[2 * EE + e] = fmaf(e1, b0, e2 * b);
        outTail[3 * EE + e] = pn;
    }
}

// ---------------------------------------------------------------------------
// WKV pass C: replay chunks from incoming state (ina layout [e*NC+c]);
// ry = sigmoid(r) in, y = sigmoid(r)*wkv out (in place).
// Vec4 over e.  grid NC*EE/4/256 blocks x 256 threads.
// ---------------------------------------------------------------------------
template <int NC>
__global__ void wkv_pass_c(const unsigned short* __restrict__ k,
                           const unsigned short* __restrict__ v,
                           const float* __restrict__ tf, const float* __restrict__ td,
                           const float* __restrict__ ina, const float* __restrict__ inb,
                           const float* __restrict__ inp,
                           unsigned short* __restrict__ ry) {
    const int CL = TT / NC;
    const int gid = blockIdx.x * 256 + threadIdx.x;
    const int c  = gid >> 8;
    const int e0 = (gid & 255) * 4;
    const float4 tdv = *(const float4*)(td + e0);
    const float4 tfv = *(const float4*)(tf + e0);
    float w[4] = { -__expf(tdv.x), -__expf(tdv.y), -__expf(tdv.z), -__expf(tdv.w) };
    float u[4] = { tfv.x, tfv.y, tfv.z, tfv.w };
    float a[4], b[4], p[4];
#pragma unroll
    for (int j = 0; j < 4; ++j) {
        a[j] = ina[(e0 + j) * NC + c];
        b[j] = inb[(e0 + j) * NC + c];
        p[j] = inp[(e0 + j) * NC + c];
    }
    const size_t base = (size_t)c * CL * EE + e0;
#pragma unroll 4
    for (int i = 0; i < CL; ++i) {
        const size_t idx = base + (size_t)i * EE;
        const ushort4 k4 = *(const ushort4*)(k + idx);
        const ushort4 v4 = *(const ushort4*)(v + idx);
        const ushort4 r4 = *(const ushort4*)(ry + idx);
        const unsigned short ks[4] = {k4.x, k4.y, k4.z, k4.w};
        const unsigned short vs[4] = {v4.x, v4.y, v4.z, v4.w};
        const unsigned short rs[4] = {r4.x, r4.y, r4.z, r4.w};
        unsigned short os[4];
#pragma unroll
        for (int j = 0; j < 4; ++j) {
            const float kk = b2f(ks[j]), vv = b2f(vs[j]), rr = b2f(rs[j]);
            const float ww = u[j] + kk;
            const float pq = fmaxf(p[j], ww);
            const float e1 = __expf(p[j] - pq), e2 = __expf(ww - pq);
            // v_rcp_f32: ~22-bit rel accuracy, output is bf16 -> exact enough
            const float wkv = fmaf(e1, a[j], e2 * vv) * __builtin_amdgcn_rcpf(fmaf(e1, b[j], e2));
            os[j] = f2bf(rr * wkv);
            const float ww2 = w[j] + p[j];
            const float p2  = fmaxf(ww2, kk);
            const float e1b = __expf(ww2 - p2), e2b = __expf(kk - p2);
            a[j] = fmaf(e1b, a[j], e2b * vv);
            b[j] = fmaf(e1b, b[j], e2b);
            p[j] = p2;
        }
        ushort4 o4;
        o4.x = os[0]; o4.y = os[1]; o4.z = os[2]; o4.w = os[3];
        *(ushort4*)(ry + idx) = o4;
    }
}

// ---------------------------------------------------------------------------
// SMALL-path serial pass B (NC=128), ina layout [e*NC+c].
// ---------------------------------------------------------------------------
__global__ void wkv_pass_b_small(const float* __restrict__ aa, const float* __restrict__ bb,
                                 const float* __restrict__ pp, const float* __restrict__ td,
                                 const float* __restrict__ x,
                                 const float* __restrict__ Sa, const float* __restrict__ Sb,
                                 const float* __restrict__ Sp,
                                 float* __restrict__ ina, float* __restrict__ inb,
                                 float* __restrict__ inp, float* __restrict__ outTail) {
    const int NC = 128, CL = TT / NC;
    const int e = blockIdx.x * 256 + threadIdx.x;
    const float w  = -__expf(td[e]);
    const float wL = w * (float)CL;
    float a = aa[e], b = bb[e], p = pp[e];
    for (int c = 0; c < NC; ++c) {
        ina[e * NC + c] = a; inb[e * NC + c] = b; inp[e * NC + c] = p;
        const int idx = c * EE + e;
        const float sa = Sa[idx], sb = Sb[idx], sp = Sp[idx];
        const float pw = p + wL;
        const float p2 = fmaxf(pw, sp);
        const float e1 = __expf(pw - p2), e2 = __expf(sp - p2);
        a = fmaf(e1, a, e2 * sa);
        b = fmaf(e1, b, e2 * sb);
        p = p2;
    }
    outTail[e]          = x[(size_t)(TT - 1) * EE + e];
    outTail[EE + e]     = a;
    outTail[2 * EE + e] = b;
    outTail[3 * EE + e] = p;
}

// ---------------------------------------------------------------------------
// SMALL path (<75 MB): fused-mix k/v/r GEMM (round-3 structure).
// ---------------------------------------------------------------------------
__global__ __launch_bounds__(256, 4) void gemm_kvr(
        const float* __restrict__ X, const float* __restrict__ SX,
        const float* __restrict__ tmk, const float* __restrict__ tmv,
        const float* __restrict__ tmr,
        const unsigned short* __restrict__ Wkt, const unsigned short* __restrict__ Wvt,
        const unsigned short* __restrict__ Wrt,
        unsigned short* __restrict__ outK, unsigned short* __restrict__ outV,
        unsigned short* __restrict__ outR) {
    __shared__ __align__(16) unsigned short As[128 * LDSK];
    __shared__ __align__(16) unsigned short Bs[128 * LDSK];
    const int z = blockIdx.z;
    const float* TM = (z == 0) ? tmk : (z == 1) ? tmv : tmr;
    const unsigned short* Bt = (z == 0) ? Wkt : (z == 1) ? Wvt : Wrt;
    unsigned short* Cout = (z == 0) ? outK : (z == 1) ? outV : outR;

    const int tid  = threadIdx.x;
    const int wave = tid >> 6, lane = tid & 63;
    const int wm = (wave >> 1) * 64, wn = (wave & 1) * 64;
    const int l15 = lane & 15, lq = lane >> 4;
    const int bm = blockIdx.x * 128, bn = blockIdx.y * 128;

    f32x4 acc[4][4] = {};

    for (int kt = 0; kt < 1024; kt += 32) {
        __syncthreads();
#pragma unroll
        for (int p = 0; p < 2; ++p) {
            const int li  = p * 256 + tid;
            const int row = li >> 2, q = li & 3;
            const int e0  = kt + q * 8;
            {
                const int t = bm + row;
                const float* xr = X + (size_t)t * EE + e0;
                const float* pr = (t > 0) ? (X + (size_t)(t - 1) * EE + e0) : (SX + e0);
                float4 xa = *(const float4*)xr, xb = *(const float4*)(xr + 4);
                float4 pa = *(const float4*)pr, pb = *(const float4*)(pr + 4);
                float4 ma = *(const float4*)(TM + e0), mb = *(const float4*)(TM + e0 + 4);
                ushort4 lo, hi;
                lo.x = f2bf(fmaf(ma.x, xa.x - pa.x, pa.x));
                lo.y = f2bf(fmaf(ma.y, xa.y - pa.y, pa.y));
                lo.z = f2bf(fmaf(ma.z, xa.z - pa.z, pa.z));
                lo.w = f2bf(fmaf(ma.w, xa.w - pa.w, pa.w));
                hi.x = f2bf(fmaf(mb.x, xb.x - pb.x, pb.x));
                hi.y = f2bf(fmaf(mb.y, xb.y - pb.y, pb.y));
                hi.z = f2bf(fmaf(mb.z, xb.z - pb.z, pb.z));
                hi.w = f2bf(fmaf(mb.w, xb.w - pb.w, pb.w));
                *(ushort4*)(&As[row * LDSK + q * 8])     = lo;
                *(ushort4*)(&As[row * LDSK + q * 8 + 4]) = hi;
            }
            *(uint4*)(&Bs[row * LDSK + q * 8]) =
                *(const uint4*)(Bt + (size_t)(bn + row) * 1024 + e0);
        }
        __syncthreads();
        bf16x8 af[4], bfr[4];
#pragma unroll
        for (int i = 0; i < 4; ++i) {
            af[i]  = *(const bf16x8*)(&As[(wm + i * 16 + l15) * LDSK + lq * 8]);
            bfr[i] = *(const bf16x8*)(&Bs[(wn + i * 16 + l15) * LDSK + lq * 8]);
        }
#pragma unroll
        for (int i = 0; i < 4; ++i)
#pragma unroll
            for (int j = 0; j < 4; ++j)
                acc[i][j] = __builtin_amdgcn_mfma_f32_16x16x32_bf16(af[i], bfr[j], acc[i][j], 0, 0, 0);
    }

    const bool sig = (z == 2);
#pragma unroll
    for (int i = 0; i < 4; ++i)
#pragma unroll
        for (int j = 0; j < 4; ++j) {
            const int col = bn + wn + j * 16 + l15;
#pragma unroll
            for (int r = 0; r < 4; ++r) {
                const int row = bm + wm + i * 16 + lq * 4 + r;
                float val = acc[i][j][r];
                if (sig) val = 1.f / (1.f + __expf(-val));
                Cout[(size_t)row * 1024 + col] = f2bf(val);
            }
        }
}

// ---------------------------------------------------------------------------
extern "C" void kernel_launch(void* const* d_in, const int* in_sizes, int n_in,
                              void* d_out, int out_size, void* d_ws, size_t ws_size,
                              hipStream_t stream) {
    const float* x   = (const float*)d_in[0];
    const float* sx  = (const float*)d_in[1];
    const float* aa  = (const float*)d_in[2];
    const float* bb  = (const float*)d_in[3];
    const float* pp  = (const float*)d_in[4];
    const float* tf  = (const float*)d_in[5];
    const float* td  = (const float*)d_in[6];
    const float* tmk = (const float*)d_in[7];
    const float* tmv = (const float*)d_in[8];
    const float* tmr = (const float*)d_in[9];
    const float* Wk  = (const float*)d_in[10];
    const float* Wv  = (const float*)d_in[11];
    const float* Wr  = (const float*)d_in[12];
    const float* Wo  = (const float*)d_in[13];
    float* out = (float*)d_out;

    char* ws = (char*)d_ws;
    const size_t MB = 1ull << 20;

    unsigned short* Wkt = (unsigned short*)(ws + 0 * MB);   // 2 MB each
    unsigned short* Wvt = (unsigned short*)(ws + 2 * MB);
    unsigned short* Wrt = (unsigned short*)(ws + 4 * MB);
    unsigned short* Wot = (unsigned short*)(ws + 6 * MB);

    if (ws_size >= 75 * MB) {
        // ws: [0:8] Wt | [8:24] rxb (scan bufs overlay after kvr3) |
        //     [24:40] kf | [40:56] ry | [56:72] vf
        unsigned short* rxb = (unsigned short*)(ws + 8 * MB);
        unsigned short* kf  = (unsigned short*)(ws + 24 * MB);
        unsigned short* ry  = (unsigned short*)(ws + 40 * MB);
        unsigned short* vf  = (unsigned short*)(ws + 56 * MB);
        // scan buffers (NC=512): 6 x 2 MB, overlaying the dead rxb region [8:20]
        float* Sa  = (float*)(ws + 8  * MB);
        float* Sb  = (float*)(ws + 10 * MB);
        float* Sp  = (float*)(ws + 12 * MB);
        float* ina = (float*)(ws + 14 * MB);
        float* inb = (float*)(ws + 16 * MB);
        float* inp = (float*)(ws + 18 * MB);
        unsigned short* kxb = (unsigned short*)d_out;                   // d_out scratch
        unsigned short* vxb = (unsigned short*)d_out + (size_t)TT * EE;

        prep_kernel<<<12288, 256, 0, stream>>>(Wk, Wv, Wr, Wo, Wkt, Wvt, Wrt, Wot,
                                               x, sx, tmk, tmv, tmr, kxb, vxb, rxb);
        gemm_kvr3<<<dim3(64, 8, 3), 256, 0, stream>>>(kxb, vxb, rxb, Wkt, Wvt, Wrt,
                                                      kf, vf, ry);
        wkv_pass_a<512><<<256, 256, 0, stream>>>(kf, vf, td, Sa, Sb, Sp);
        wkv_pass_b_par<512><<<EE, 512, 0, stream>>>(aa, bb, pp, td, x, Sa, Sb, Sp,
                                                    ina, inb, inp, out + (size_t)TT * EE);
        wkv_pass_c<512><<<512, 256, 0, stream>>>(kf, vf, tf, td,
                                                 ina, inb, inp, ry);
        gemm_wo<<<dim3(64, 8), 256, 0, stream>>>(ry, Wot, x, out);
    } else {
        // 27 MB proven fallback (NC=128)
        unsigned short* ry = (unsigned short*)(ws + 8 * MB);
        char* scan = ws + 24 * MB;
        const size_t QK = (size_t)128 * EE * sizeof(float);  // 512 KB
        float* Sa  = (float*)(scan);
        float* Sb  = (float*)(scan + QK);
        float* Sp  = (float*)(scan + 2 * QK);
        float* ina = (float*)(scan + 3 * QK);
        float* inb = (float*)(scan + 4 * QK);
        float* inp = (float*)(scan + 5 * QK);
        unsigned short* kf = (unsigned short*)d_out;
        unsigned short* vf = (unsigned short*)d_out + (size_t)TT * EE;

        wt_kernel<<<dim3(32, 32, 4), dim3(32, 8), 0, stream>>>(Wk, Wv, Wr, Wo, Wkt, Wvt, Wrt, Wot);
        gemm_kvr<<<dim3(64, 8, 3), 256, 0, stream>>>(x, sx, tmk, tmv, tmr,
                                                     Wkt, Wvt, Wrt, kf, vf, ry);
        wkv_pass_a<128><<<64, 256, 0, stream>>>(kf, vf, td, Sa, Sb, Sp);
        wkv_pass_b_small<<<4, 256, 0, stream>>>(aa, bb, pp, td, x, Sa, Sb, Sp,
                                                ina, inb, inp, out + (size_t)TT * EE);
        wkv_pass_c<128><<<128, 256, 0, stream>>>(kf, vf, tf, td,
                                                 ina, inb, inp, ry);
        gemm_wo<<<dim3(64, 8), 256, 0, stream>>>(ry, Wot, x, out);
    }
}

// Round 5
// 242.455 us; speedup vs baseline: 2.1916x; 1.1231x over previous
//
#include <hip/hip_runtime.h>
#include <cstdint>
#include <cstddef>

typedef __bf16 bf16x8 __attribute__((ext_vector_type(8)));
typedef float  f32x4  __attribute__((ext_vector_type(4)));

#define TT 8192
#define EE 1024
#define LDSK 40    // small-path padded LDS stride (shorts)

__device__ __forceinline__ unsigned short f2bf(float f) {
    union { float f; unsigned int u; } v; v.f = f;
    unsigned int r = v.u + 0x7FFFu + ((v.u >> 16) & 1u);
    return (unsigned short)(r >> 16);
}
__device__ __forceinline__ float b2f(unsigned int h) {
    union { unsigned int u; float f; } v; v.u = h << 16; return v.f;
}
__device__ __forceinline__ void gload_lds16(const void* g, void* l) {
    __builtin_amdgcn_global_load_lds((__attribute__((address_space(1))) void*)g,
                                     (__attribute__((address_space(3))) void*)l, 16, 0, 0);
}

// ---------------------------------------------------------------------------
// Standalone W transpose (small path). grid (32,32,4), block (32,8).
// ---------------------------------------------------------------------------
__global__ void wt_kernel(const float* __restrict__ Wk, const float* __restrict__ Wv,
                          const float* __restrict__ Wr, const float* __restrict__ Wo,
                          unsigned short* __restrict__ Tk, unsigned short* __restrict__ Tv,
                          unsigned short* __restrict__ Tr, unsigned short* __restrict__ To) {
    __shared__ float tile[32][33];
    const float* W; unsigned short* D;
    switch (blockIdx.z) {
        case 0:  W = Wk; D = Tk; break;
        case 1:  W = Wv; D = Tv; break;
        case 2:  W = Wr; D = Tr; break;
        default: W = Wo; D = To; break;
    }
    const int bx = blockIdx.x * 32, by = blockIdx.y * 32;
    const int tx = threadIdx.x, ty = threadIdx.y;
#pragma unroll
    for (int r = 0; r < 4; ++r)
        tile[ty + 8 * r][tx] = W[(size_t)(by + ty + 8 * r) * EE + bx + tx];
    __syncthreads();
#pragma unroll
    for (int r = 0; r < 4; ++r)
        D[(size_t)(bx + ty + 8 * r) * EE + by + tx] = f2bf(tile[tx][ty + 8 * r]);
}

// ---------------------------------------------------------------------------
// Fused prep: blocks [0,4096) transpose 4 Ws; blocks [4096,12288) token-shift
// mix -> bf16 kx/vx/rx.  1D grid 12288, block 256.
// ---------------------------------------------------------------------------
__global__ void prep_kernel(const float* __restrict__ Wk, const float* __restrict__ Wv,
                            const float* __restrict__ Wr, const float* __restrict__ Wo,
                            unsigned short* __restrict__ Tk, unsigned short* __restrict__ Tv,
                            unsigned short* __restrict__ Tr, unsigned short* __restrict__ To,
                            const float* __restrict__ x, const float* __restrict__ sx,
                            const float* __restrict__ tmk, const float* __restrict__ tmv,
                            const float* __restrict__ tmr,
                            unsigned short* __restrict__ kxb, unsigned short* __restrict__ vxb,
                            unsigned short* __restrict__ rxb) {
    const int bid = blockIdx.x;
    if (bid < 4096) {
        __shared__ float tile[32][33];
        const int z = bid >> 10;
        const float* W; unsigned short* D;
        switch (z) {
            case 0:  W = Wk; D = Tk; break;
            case 1:  W = Wv; D = Tv; break;
            case 2:  W = Wr; D = Tr; break;
            default: W = Wo; D = To; break;
        }
        const int by = ((bid >> 5) & 31) * 32, bx = (bid & 31) * 32;
        const int tx = threadIdx.x & 31, ty = threadIdx.x >> 5;
#pragma unroll
        for (int r = 0; r < 4; ++r)
            tile[ty + 8 * r][tx] = W[(size_t)(by + ty + 8 * r) * EE + bx + tx];
        __syncthreads();
#pragma unroll
        for (int r = 0; r < 4; ++r)
            D[(size_t)(bx + ty + 8 * r) * EE + by + tx] = f2bf(tile[tx][ty + 8 * r]);
    } else {
        const int gid  = (bid - 4096) * 256 + threadIdx.x;
        const int base = gid * 4;
        const int t = base >> 10;
        const int e = base & (EE - 1);
        float4 xv = *(const float4*)(x + base);
        float4 pv = (t > 0) ? *(const float4*)(x + base - EE) : *(const float4*)(sx + e);
        float4 mk = *(const float4*)(tmk + e);
        float4 mv = *(const float4*)(tmv + e);
        float4 mr = *(const float4*)(tmr + e);
        ushort4 ko, vo, ro;
        ko.x = f2bf(fmaf(mk.x, xv.x - pv.x, pv.x));
        ko.y = f2bf(fmaf(mk.y, xv.y - pv.y, pv.y));
        ko.z = f2bf(fmaf(mk.z, xv.z - pv.z, pv.z));
        ko.w = f2bf(fmaf(mk.w, xv.w - pv.w, pv.w));
        vo.x = f2bf(fmaf(mv.x, xv.x - pv.x, pv.x));
        vo.y = f2bf(fmaf(mv.y, xv.y - pv.y, pv.y));
        vo.z = f2bf(fmaf(mv.z, xv.z - pv.z, pv.z));
        vo.w = f2bf(fmaf(mv.w, xv.w - pv.w, pv.w));
        ro.x = f2bf(fmaf(mr.x, xv.x - pv.x, pv.x));
        ro.y = f2bf(fmaf(mr.y, xv.y - pv.y, pv.y));
        ro.z = f2bf(fmaf(mr.z, xv.z - pv.z, pv.z));
        ro.w = f2bf(fmaf(mr.w, xv.w - pv.w, pv.w));
        *(ushort4*)(kxb + base) = ko;
        *(ushort4*)(vxb + base) = vo;
        *(ushort4*)(rxb + base) = ro;
    }
}

// ---------------------------------------------------------------------------
// 128x128-tile bf16 GEMM, BK=64, 2-barrier K-loop (16 iters), XOR-swizzled
// LDS.  3 operand sets via blockIdx.z (z==2 -> sigmoid).  grid (64,8,3).
// PROVEN structure (~58 us healthy node).  UNCHANGED: control.
// ---------------------------------------------------------------------------
__global__ __launch_bounds__(256, 4) void gemm_kvr3(
        const unsigned short* __restrict__ kxb, const unsigned short* __restrict__ vxb,
        const unsigned short* __restrict__ rxb,
        const unsigned short* __restrict__ Wkt, const unsigned short* __restrict__ Wvt,
        const unsigned short* __restrict__ Wrt,
        unsigned short* __restrict__ kf, unsigned short* __restrict__ vf,
        unsigned short* __restrict__ ry) {
    __shared__ __align__(16) unsigned short As[128 * 64];   // 16 KB
    __shared__ __align__(16) unsigned short Bs[128 * 64];   // 16 KB
    const int z = blockIdx.z;
    const unsigned short* A  = (z == 0) ? kxb : (z == 1) ? vxb : rxb;
    const unsigned short* Bt = (z == 0) ? Wkt : (z == 1) ? Wvt : Wrt;
    unsigned short* C        = (z == 0) ? kf  : (z == 1) ? vf  : ry;

    const int tid  = threadIdx.x;
    const int wave = tid >> 6, lane = tid & 63;
    const int wm = (wave >> 1) * 64, wn = (wave & 1) * 64;
    const int l15 = lane & 15, lq = lane >> 4;
    const int lrow = lane >> 3;                          // 8 lanes/row, 8 rows/instr
    const int lcolg = (((lane & 7) ^ lrow) & 7) * 8;     // swizzled global col group
    const int sw = l15 & 7;                              // read-side swizzle key
    const int bm = blockIdx.x * 128, bn = blockIdx.y * 128;

    f32x4 acc[4][4] = {};

    for (int kt = 0; kt < 1024; kt += 64) {
        __syncthreads();
#pragma unroll
        for (int p = 0; p < 4; ++p) {
            const int r0 = p * 32 + wave * 8;
            gload_lds16(A  + (size_t)(bm + r0 + lrow) * 1024 + kt + lcolg, &As[r0 * 64]);
            gload_lds16(Bt + (size_t)(bn + r0 + lrow) * 1024 + kt + lcolg, &Bs[r0 * 64]);
        }
        __syncthreads();
#pragma unroll
        for (int h = 0; h < 2; ++h) {
            bf16x8 af[4], bfr[4];
#pragma unroll
            for (int i = 0; i < 4; ++i) {
                const int g = ((h * 4 + lq) ^ sw) * 8;
                af[i]  = *(const bf16x8*)(&As[(wm + i * 16 + l15) * 64 + g]);
                bfr[i] = *(const bf16x8*)(&Bs[(wn + i * 16 + l15) * 64 + g]);
            }
#pragma unroll
            for (int i = 0; i < 4; ++i)
#pragma unroll
                for (int j = 0; j < 4; ++j)
                    acc[i][j] = __builtin_amdgcn_mfma_f32_16x16x32_bf16(af[i], bfr[j], acc[i][j], 0, 0, 0);
        }
    }

    const bool sig = (z == 2);
#pragma unroll
    for (int i = 0; i < 4; ++i)
#pragma unroll
        for (int j = 0; j < 4; ++j) {
            const int col = bn + wn + j * 16 + l15;
#pragma unroll
            for (int r = 0; r < 4; ++r) {
                const int row = bm + wm + i * 16 + lq * 4 + r;
                float val = acc[i][j][r];
                if (sig) val = 1.f / (1.f + __expf(-val));
                C[(size_t)row * 1024 + col] = f2bf(val);
            }
        }
}

// ---------------------------------------------------------------------------
// Wo GEMM: 128x128 tile, BK=64, XOR-swizzled LDS.  C f32 = A bf16 @ Bt^T + Res.
// grid (64,8) = 512 blocks.  UNCHANGED: control.
// ---------------------------------------------------------------------------
__global__ __launch_bounds__(256, 4) void gemm_wo(const unsigned short* __restrict__ A,
                                                  const unsigned short* __restrict__ Bt,
                                                  const float* __restrict__ Res,
                                                  float* __restrict__ C) {
    __shared__ __align__(16) unsigned short As[128 * 64];   // 16 KB
    __shared__ __align__(16) unsigned short Bs[128 * 64];   // 16 KB
    const int tid  = threadIdx.x;
    const int wave = tid >> 6, lane = tid & 63;
    const int wm = (wave >> 1) * 64, wn = (wave & 1) * 64;
    const int l15 = lane & 15, lq = lane >> 4;
    const int lrow = lane >> 3;
    const int lcolg = (((lane & 7) ^ lrow) & 7) * 8;
    const int sw = l15 & 7;
    const int bm = blockIdx.x * 128, bn = blockIdx.y * 128;

    f32x4 acc[4][4] = {};

    for (int kt = 0; kt < 1024; kt += 64) {
        __syncthreads();
#pragma unroll
        for (int p = 0; p < 4; ++p) {
            const int r0 = p * 32 + wave * 8;
            gload_lds16(A  + (size_t)(bm + r0 + lrow) * 1024 + kt + lcolg, &As[r0 * 64]);
            gload_lds16(Bt + (size_t)(bn + r0 + lrow) * 1024 + kt + lcolg, &Bs[r0 * 64]);
        }
        __syncthreads();
#pragma unroll
        for (int h = 0; h < 2; ++h) {
            bf16x8 af[4], bfr[4];
#pragma unroll
            for (int i = 0; i < 4; ++i) {
                const int g = ((h * 4 + lq) ^ sw) * 8;
                af[i]  = *(const bf16x8*)(&As[(wm + i * 16 + l15) * 64 + g]);
                bfr[i] = *(const bf16x8*)(&Bs[(wn + i * 16 + l15) * 64 + g]);
            }
#pragma unroll
            for (int i = 0; i < 4; ++i)
#pragma unroll
                for (int j = 0; j < 4; ++j)
                    acc[i][j] = __builtin_amdgcn_mfma_f32_16x16x32_bf16(af[i], bfr[j], acc[i][j], 0, 0, 0);
        }
    }

#pragma unroll
    for (int i = 0; i < 4; ++i)
#pragma unroll
        for (int j = 0; j < 4; ++j) {
            const int col = bn + wn + j * 16 + l15;
#pragma unroll
            for (int r = 0; r < 4; ++r) {
                const int row = bm + wm + i * 16 + lq * 4 + r;
                const size_t idx = (size_t)row * 1024 + col;
                C[idx] = acc[i][j][r] + Res[idx];
            }
        }
}

// ---------------------------------------------------------------------------
// WKV pass A: per (chunk, channel-pair) stabilized local summary.
// V=2 (uint 4B loads) at 4 waves/SIMD occupancy: grid NC*2 blocks x 256.
// Occupancy > load-width for this latency-bound serial-chain kernel
// (round-4 lesson: vec8 @ 1 wave/SIMD regressed ~35 us).
// ---------------------------------------------------------------------------
template <int NC>
__global__ void wkv_pass_a(const unsigned short* __restrict__ k,
                           const unsigned short* __restrict__ v,
                           const float* __restrict__ td,
                           float* __restrict__ Sa, float* __restrict__ Sb,
                           float* __restrict__ Sp) {
    const int CL = TT / NC;
    const int gid = blockIdx.x * 256 + threadIdx.x;
    const int c  = gid >> 9;             // EE/2 = 512 pairs per chunk
    const int e0 = (gid & 511) * 2;
    const float2 tdv = *(const float2*)(td + e0);
    float w[2] = { -__expf(tdv.x), -__expf(tdv.y) };
    float sa[2] = {0.f, 0.f}, sb[2] = {0.f, 0.f}, sp[2] = {-1e30f, -1e30f};
    const size_t base = (size_t)c * CL * EE + e0;
#pragma unroll
    for (int i = 0; i < CL; ++i) {
        const unsigned int k2 = *(const unsigned int*)(k + base + (size_t)i * EE);
        const unsigned int v2 = *(const unsigned int*)(v + base + (size_t)i * EE);
        const unsigned short ks[2] = { (unsigned short)(k2 & 0xffffu),
                                       (unsigned short)(k2 >> 16) };
        const unsigned short vs[2] = { (unsigned short)(v2 & 0xffffu),
                                       (unsigned short)(v2 >> 16) };
        const float fi = (float)(CL - 1 - i);
#pragma unroll
        for (int j = 0; j < 2; ++j) {
            const float kk = b2f(ks[j]), vv = b2f(vs[j]);
            const float q  = fmaf(w[j], fi, kk);
            const float p2 = fmaxf(sp[j], q);
            const float e1 = __expf(sp[j] - p2), e2 = __expf(q - p2);
            sa[j] = fmaf(e1, sa[j], e2 * vv);
            sb[j] = fmaf(e1, sb[j], e2);
            sp[j] = p2;
        }
    }
    float2 o;
    o.x = sa[0]; o.y = sa[1]; *(float2*)(Sa + c * EE + e0) = o;
    o.x = sb[0]; o.y = sb[1]; *(float2*)(Sb + c * EE + e0) = o;
    o.x = sp[0]; o.y = sp[1]; *(float2*)(Sp + c * EE + e0) = o;
}

// ---------------------------------------------------------------------------
// WKV pass B (parallel): Kogge-Stone scan over NC chunk summaries per
// channel.  grid EE blocks x NC threads.  ina/inb/inp layout: [e*NC + c].
// ---------------------------------------------------------------------------
template <int NC>
__global__ void wkv_pass_b_par(const float* __restrict__ aa, const float* __restrict__ bb,
                               const float* __restrict__ pp, const float* __restrict__ td,
                               const float* __restrict__ x,
                               const float* __restrict__ Sa, const float* __restrict__ Sb,
                               const float* __restrict__ Sp,
                               float* __restrict__ ina, float* __restrict__ inb,
                               float* __restrict__ inp, float* __restrict__ outTail) {
    const int CL = TT / NC;
    const int e = blockIdx.x, c = threadIdx.x;
    __shared__ float sA[NC], sB[NC], sP[NC];
    const float w = -__expf(td[e]);

    float a = Sa[c * EE + e], b = Sb[c * EE + e], p = Sp[c * EE + e];

    for (int s = 1; s < NC; s <<= 1) {
        sA[c] = a; sB[c] = b; sP[c] = p;
        __syncthreads();
        if (c >= s) {
            const float myLen = (float)(CL * min(c + 1, s));
            const float aL = sA[c - s], bL = sB[c - s], pL = sP[c - s];
            const float pLd = pL + w * myLen;
            const float pn  = fmaxf(pLd, p);
            const float e1  = __expf(pLd - pn), e2 = __expf(p - pn);
            a = fmaf(e1, aL, e2 * a);
            b = fmaf(e1, bL, e2 * b);
            p = pn;
        }
        __syncthreads();
    }

    sA[c] = a; sB[c] = b; sP[c] = p;
    __syncthreads();

    const float a0 = aa[e], b0 = bb[e], p0 = pp[e];
    float ea, eb, ep;
    if (c == 0) { ea = a0; eb = b0; ep = p0; }
    else {
        const float aL = sA[c - 1], bL = sB[c - 1], pL = sP[c - 1];
        const float p0d = p0 + w * (float)(c * CL);
        const float pn  = fmaxf(p0d, pL);
        const float e1  = __expf(p0d - pn), e2 = __expf(pL - pn);
        ea = fmaf(e1, a0, e2 * aL);
        eb = fmaf(e1, b0, e2 * bL);
        ep = pn;
    }
    ina[e * NC + c] = ea; inb[e * NC + c] = eb; inp[e * NC + c] = ep;

    if (c == NC - 1) {
        const float p0d = p0 + w * (float)TT;
        const float pn  = fmaxf(p0d, p);
        const float e1  = __expf(p0d - pn), e2 = __expf(p - pn);
        outTail[e]          = x[(size_t)(TT - 1) * EE + e];
        outTail[EE + e]     = fmaf(e1, a0, e2 * a);
        outTail[2 * EE + e] = fmaf(e1, b0, e2 * b);
        outTail[3 * EE + e] = pn;
    }
}

// ---------------------------------------------------------------------------
// WKV pass C: replay chunks from incoming state (ina layout [e*NC+c]);
// ry = sigmoid(r) in, y = sigmoid(r)*wkv out (in place).
// V=2 at 4 waves/SIMD: grid NC*2 blocks x 256 threads.
// ---------------------------------------------------------------------------
template <int NC>
__global__ void wkv_pass_c(const unsigned short* __restrict__ k,
                           const unsigned short* __restrict__ v,
                           const float* __restrict__ tf, const float* __restrict__ td,
                           const float* __restrict__ ina, const float* __restrict__ inb,
                           const float* __restrict__ inp,
                           unsigned short* __restrict__ ry) {
    const int CL = TT / NC;
    const int gid = blockIdx.x * 256 + threadIdx.x;
    const int c  = gid >> 9;
    const int e0 = (gid & 511) * 2;
    const float2 tdv = *(const float2*)(td + e0);
    const float2 tfv = *(const float2*)(tf + e0);
    float w[2] = { -__expf(tdv.x), -__expf(tdv.y) };
    float u[2] = { tfv.x, tfv.y };
    float a[2], b[2], p[2];
#pragma unroll
    for (int j = 0; j < 2; ++j) {
        a[j] = ina[(e0 + j) * NC + c];
        b[j] = inb[(e0 + j) * NC + c];
        p[j] = inp[(e0 + j) * NC + c];
    }
    const size_t base = (size_t)c * CL * EE + e0;
#pragma unroll 4
    for (int i = 0; i < CL; ++i) {
        const size_t idx = base + (size_t)i * EE;
        const unsigned int k2 = *(const unsigned int*)(k + idx);
        const unsigned int v2 = *(const unsigned int*)(v + idx);
        const unsigned int r2 = *(const unsigned int*)(ry + idx);
        const unsigned short ks[2] = { (unsigned short)(k2 & 0xffffu),
                                       (unsigned short)(k2 >> 16) };
        const unsigned short vs[2] = { (unsigned short)(v2 & 0xffffu),
                                       (unsigned short)(v2 >> 16) };
        const unsigned short rs[2] = { (unsigned short)(r2 & 0xffffu),
                                       (unsigned short)(r2 >> 16) };
        unsigned short os[2];
#pragma unroll
        for (int j = 0; j < 2; ++j) {
            const float kk = b2f(ks[j]), vv = b2f(vs[j]), rr = b2f(rs[j]);
            const float ww = u[j] + kk;
            const float pq = fmaxf(p[j], ww);
            const float e1 = __expf(p[j] - pq), e2 = __expf(ww - pq);
            // v_rcp_f32: ~22-bit rel accuracy, output is bf16 -> exact enough
            const float wkv = fmaf(e1, a[j], e2 * vv) * __builtin_amdgcn_rcpf(fmaf(e1, b[j], e2));
            os[j] = f2bf(rr * wkv);
            const float ww2 = w[j] + p[j];
            const float p2  = fmaxf(ww2, kk);
            const float e1b = __expf(ww2 - p2), e2b = __expf(kk - p2);
            a[j] = fmaf(e1b, a[j], e2b * vv);
            b[j] = fmaf(e1b, b[j], e2b);
            p[j] = p2;
        }
        *(unsigned int*)(ry + idx) = (unsigned int)os[0] | ((unsigned int)os[1] << 16);
    }
}

// ---------------------------------------------------------------------------
// SMALL-path serial pass B (NC=128), ina layout [e*NC+c].
// ---------------------------------------------------------------------------
__global__ void wkv_pass_b_small(const float* __restrict__ aa, const float* __restrict__ bb,
                                 const float* __restrict__ pp, const float* __restrict__ td,
                                 const float* __restrict__ x,
                                 const float* __restrict__ Sa, const float* __restrict__ Sb,
                                 const float* __restrict__ Sp,
                                 float* __restrict__ ina, float* __restrict__ inb,
                                 float* __restrict__ inp, float* __restrict__ outTail) {
    const int NC = 128, CL = TT / NC;
    const int e = blockIdx.x * 256 + threadIdx.x;
    const float w  = -__expf(td[e]);
    const float wL = w * (float)CL;
    float a = aa[e], b = bb[e], p = pp[e];
    for (int c = 0; c < NC; ++c) {
        ina[e * NC + c] = a; inb[e * NC + c] = b; inp[e * NC + c] = p;
        const int idx = c * EE + e;
        const float sa = Sa[idx], sb = Sb[idx], sp = Sp[idx];
        const float pw = p + wL;
        const float p2 = fmaxf(pw, sp);
        const float e1 = __expf(pw - p2), e2 = __expf(sp - p2);
        a = fmaf(e1, a, e2 * sa);
        b = fmaf(e1, b, e2 * sb);
        p = p2;
    }
    outTail[e]          = x[(size_t)(TT - 1) * EE + e];
    outTail[EE + e]     = a;
    outTail[2 * EE + e] = b;
    outTail[3 * EE + e] = p;
}

// ---------------------------------------------------------------------------
// SMALL path (<75 MB): fused-mix k/v/r GEMM (round-3 structure).
// ---------------------------------------------------------------------------
__global__ __launch_bounds__(256, 4) void gemm_kvr(
        const float* __restrict__ X, const float* __restrict__ SX,
        const float* __restrict__ tmk, const float* __restrict__ tmv,
        const float* __restrict__ tmr,
        const unsigned short* __restrict__ Wkt, const unsigned short* __restrict__ Wvt,
        const unsigned short* __restrict__ Wrt,
        unsigned short* __restrict__ outK, unsigned short* __restrict__ outV,
        unsigned short* __restrict__ outR) {
    __shared__ __align__(16) unsigned short As[128 * LDSK];
    __shared__ __align__(16) unsigned short Bs[128 * LDSK];
    const int z = blockIdx.z;
    const float* TM = (z == 0) ? tmk : (z == 1) ? tmv : tmr;
    const unsigned short* Bt = (z == 0) ? Wkt : (z == 1) ? Wvt : Wrt;
    unsigned short* Cout = (z == 0) ? outK : (z == 1) ? outV : outR;

    const int tid  = threadIdx.x;
    const int wave = tid >> 6, lane = tid & 63;
    const int wm = (wave >> 1) * 64, wn = (wave & 1) * 64;
    const int l15 = lane & 15, lq = lane >> 4;
    const int bm = blockIdx.x * 128, bn = blockIdx.y * 128;

    f32x4 acc[4][4] = {};

    for (int kt = 0; kt < 1024; kt += 32) {
        __syncthreads();
#pragma unroll
        for (int p = 0; p < 2; ++p) {
            const int li  = p * 256 + tid;
            const int row = li >> 2, q = li & 3;
            const int e0  = kt + q * 8;
            {
                const int t = bm + row;
                const float* xr = X + (size_t)t * EE + e0;
                const float* pr = (t > 0) ? (X + (size_t)(t - 1) * EE + e0) : (SX + e0);
                float4 xa = *(const float4*)xr, xb = *(const float4*)(xr + 4);
                float4 pa = *(const float4*)pr, pb = *(const float4*)(pr + 4);
                float4 ma = *(const float4*)(TM + e0), mb = *(const float4*)(TM + e0 + 4);
                ushort4 lo, hi;
                lo.x = f2bf(fmaf(ma.x, xa.x - pa.x, pa.x));
                lo.y = f2bf(fmaf(ma.y, xa.y - pa.y, pa.y));
                lo.z = f2bf(fmaf(ma.z, xa.z - pa.z, pa.z));
                lo.w = f2bf(fmaf(ma.w, xa.w - pa.w, pa.w));
                hi.x = f2bf(fmaf(mb.x, xb.x - pb.x, pb.x));
                hi.y = f2bf(fmaf(mb.y, xb.y - pb.y, pb.y));
                hi.z = f2bf(fmaf(mb.z, xb.z - pb.z, pb.z));
                hi.w = f2bf(fmaf(mb.w, xb.w - pb.w, pb.w));
                *(ushort4*)(&As[row * LDSK + q * 8])     = lo;
                *(ushort4*)(&As[row * LDSK + q * 8 + 4]) = hi;
            }
            *(uint4*)(&Bs[row * LDSK + q * 8]) =
                *(const uint4*)(Bt + (size_t)(bn + row) * 1024 + e0);
        }
        __syncthreads();
        bf16x8 af[4], bfr[4];
#pragma unroll
        for (int i = 0; i < 4; ++i) {
            af[i]  = *(const bf16x8*)(&As[(wm + i * 16 + l15) * LDSK + lq * 8]);
            bfr[i] = *(const bf16x8*)(&Bs[(wn + i * 16 + l15) * LDSK + lq * 8]);
        }
#pragma unroll
        for (int i = 0; i < 4; ++i)
#pragma unroll
            for (int j = 0; j < 4; ++j)
                acc[i][j] = __builtin_amdgcn_mfma_f32_16x16x32_bf16(af[i], bfr[j], acc[i][j], 0, 0, 0);
    }

    const bool sig = (z == 2);
#pragma unroll
    for (int i = 0; i < 4; ++i)
#pragma unroll
        for (int j = 0; j < 4; ++j) {
            const int col = bn + wn + j * 16 + l15;
#pragma unroll
            for (int r = 0; r < 4; ++r) {
                const int row = bm + wm + i * 16 + lq * 4 + r;
                float val = acc[i][j][r];
                if (sig) val = 1.f / (1.f + __expf(-val));
                Cout[(size_t)row * 1024 + col] = f2bf(val);
            }
        }
}

// ---------------------------------------------------------------------------
extern "C" void kernel_launch(void* const* d_in, const int* in_sizes, int n_in,
                              void* d_out, int out_size, void* d_ws, size_t ws_size,
                              hipStream_t stream) {
    const float* x   = (const float*)d_in[0];
    const float* sx  = (const float*)d_in[1];
    const float* aa  = (const float*)d_in[2];
    const float* bb  = (const float*)d_in[3];
    const float* pp  = (const float*)d_in[4];
    const float* tf  = (const float*)d_in[5];
    const float* td  = (const float*)d_in[6];
    const float* tmk = (const float*)d_in[7];
    const float* tmv = (const float*)d_in[8];
    const float* tmr = (const float*)d_in[9];
    const float* Wk  = (const float*)d_in[10];
    const float* Wv  = (const float*)d_in[11];
    const float* Wr  = (const float*)d_in[12];
    const float* Wo  = (const float*)d_in[13];
    float* out = (float*)d_out;

    char* ws = (char*)d_ws;
    const size_t MB = 1ull << 20;

    unsigned short* Wkt = (unsigned short*)(ws + 0 * MB);   // 2 MB each
    unsigned short* Wvt = (unsigned short*)(ws + 2 * MB);
    unsigned short* Wrt = (unsigned short*)(ws + 4 * MB);
    unsigned short* Wot = (unsigned short*)(ws + 6 * MB);

    if (ws_size >= 75 * MB) {
        // ws: [0:8] Wt | [8:24] rxb (scan bufs overlay after kvr3) |
        //     [24:40] kf | [40:56] ry | [56:72] vf
        unsigned short* rxb = (unsigned short*)(ws + 8 * MB);
        unsigned short* kf  = (unsigned short*)(ws + 24 * MB);
        unsigned short* ry  = (unsigned short*)(ws + 40 * MB);
        unsigned short* vf  = (unsigned short*)(ws + 56 * MB);
        // scan buffers (NC=512): 6 x 2 MB, overlaying the dead rxb region [8:20]
        float* Sa  = (float*)(ws + 8  * MB);
        float* Sb  = (float*)(ws + 10 * MB);
        float* Sp  = (float*)(ws + 12 * MB);
        float* ina = (float*)(ws + 14 * MB);
        float* inb = (float*)(ws + 16 * MB);
        float* inp = (float*)(ws + 18 * MB);
        unsigned short* kxb = (unsigned short*)d_out;                   // d_out scratch
        unsigned short* vxb = (unsigned short*)d_out + (size_t)TT * EE;

        prep_kernel<<<12288, 256, 0, stream>>>(Wk, Wv, Wr, Wo, Wkt, Wvt, Wrt, Wot,
                                               x, sx, tmk, tmv, tmr, kxb, vxb, rxb);
        gemm_kvr3<<<dim3(64, 8, 3), 256, 0, stream>>>(kxb, vxb, rxb, Wkt, Wvt, Wrt,
                                                      kf, vf, ry);
        wkv_pass_a<512><<<1024, 256, 0, stream>>>(kf, vf, td, Sa, Sb, Sp);
        wkv_pass_b_par<512><<<EE, 512, 0, stream>>>(aa, bb, pp, td, x, Sa, Sb, Sp,
                                                    ina, inb, inp, out + (size_t)TT * EE);
        wkv_pass_c<512><<<1024, 256, 0, stream>>>(kf, vf, tf, td,
                                                  ina, inb, inp, ry);
        gemm_wo<<<dim3(64, 8), 256, 0, stream>>>(ry, Wot, x, out);
    } else {
        // 27 MB proven fallback (NC=128)
        unsigned short* ry = (unsigned short*)(ws + 8 * MB);
        char* scan = ws + 24 * MB;
        const size_t QK = (size_t)128 * EE * sizeof(float);  // 512 KB
        float* Sa  = (float*)(scan);
        float* Sb  = (float*)(scan + QK);
        float* Sp  = (float*)(scan + 2 * QK);
        float* ina = (float*)(scan + 3 * QK);
        float* inb = (float*)(scan + 4 * QK);
        float* inp = (float*)(scan + 5 * QK);
        unsigned short* kf = (unsigned short*)d_out;
        unsigned short* vf = (unsigned short*)d_out + (size_t)TT * EE;

        wt_kernel<<<dim3(32, 32, 4), dim3(32, 8), 0, stream>>>(Wk, Wv, Wr, Wo, Wkt, Wvt, Wrt, Wot);
        gemm_kvr<<<dim3(64, 8, 3), 256, 0, stream>>>(x, sx, tmk, tmv, tmr,
                                                     Wkt, Wvt, Wrt, kf, vf, ry);
        wkv_pass_a<128><<<256, 256, 0, stream>>>(kf, vf, td, Sa, Sb, Sp);
        wkv_pass_b_small<<<4, 256, 0, stream>>>(aa, bb, pp, td, x, Sa, Sb, Sp,
                                                ina, inb, inp, out + (size_t)TT * EE);
        wkv_pass_c<128><<<256, 256, 0, stream>>>(kf, vf, tf, td,
                                                 ina, inb, inp, ry);
        gemm_wo<<<dim3(64, 8), 256, 0, stream>>>(ry, Wot, x, out);
    }
}